// Round 5
// baseline (357.021 us; speedup 1.0000x reference)
//
#include <hip/hip_runtime.h>
#include <stdint.h>

// TransformerBlock on MI355X (gfx950), bf16-MFMA. Round 5.
// vs R4: flash_attn gets KV-split x4 (flash-decoding) -> 4x waves for latency
// hiding; tree-shaped softmax reductions; merge of partials fused into LN1.
// Workspace re-laid out with explicit offsets (68 MiB, partials alias dead bufs).

#define NTOK 2048
#define DMODEL 1024
#define NHEAD 16
#define DHEAD 64
#define DFF 4096
#define NSPLIT 4

typedef __attribute__((ext_vector_type(8))) short short8;
typedef __attribute__((ext_vector_type(4))) short short4v;
typedef __attribute__((ext_vector_type(4))) float f32x4;

__device__ __forceinline__ float fexp2(float x) { return __builtin_amdgcn_exp2f(x); }

// fp32 -> bf16 RNE
__device__ __forceinline__ short f2b(float f) {
  union { float f; unsigned u; } v; v.f = f;
  unsigned r = v.u + 0x7fffu + ((v.u >> 16) & 1u);
  return (short)(r >> 16);
}

__device__ __forceinline__ void gload_lds16(const void* g, void* l) {
  __builtin_amdgcn_global_load_lds((const __attribute__((address_space(1))) void*)g,
                                   (__attribute__((address_space(3))) void*)l,
                                   16, 0, 0);
}

// ---------------- fused cast fp32 -> bf16 for 4 tensors ----------------
__global__ void cast_all(const float* __restrict__ s0, short* __restrict__ d0, int n0,
                         const float* __restrict__ s1, short* __restrict__ d1, int n1,
                         const float* __restrict__ s2, short* __restrict__ d2, int n2,
                         const float* __restrict__ s3, short* __restrict__ d3, int n3) {
  int i = blockIdx.x * blockDim.x + threadIdx.x;
  const float* s; short* d; int j = i;
  if (j < n0) { s = s0; d = d0; }
  else { j -= n0;
    if (j < n1) { s = s1; d = d1; }
    else { j -= n1;
      if (j < n2) { s = s2; d = d2; }
      else { j -= n2; if (j >= n3) return; s = s3; d = d3; }
    }
  }
  const float4* p = (const float4*)(s + (size_t)j * 8);
  float4 a = p[0], b = p[1];
  short8 o;
  o[0] = f2b(a.x); o[1] = f2b(a.y); o[2] = f2b(a.z); o[3] = f2b(a.w);
  o[4] = f2b(b.x); o[5] = f2b(b.y); o[6] = f2b(b.z); o[7] = f2b(b.w);
  *(short8*)(d + (size_t)j * 8) = o;
}

// ---------------- GEMM: C = A @ B^T (+relu/bias), bf16 in, f32 acc ----------------
template<int BM, int BN, int WR, int WC, bool BF16OUT, bool BIAS, bool RELU>
__launch_bounds__(WR * WC * 64)
__global__ void gemm_bt(const short* __restrict__ A, const short* __restrict__ B,
                        const float* __restrict__ bias,
                        float* __restrict__ Cf, short* __restrict__ Cb,
                        int M, int N, int K, int lda, int ldb, int kstep) {
  constexpr int BK = 32;
  constexpr int THREADS = WR * WC * 64;
  constexpr int AISS = (BM * BK) / (8 * THREADS);
  constexpr int BISS = (BN * BK) / (8 * THREADS);
  __shared__ short As[BM * BK];
  __shared__ short Bs[BN * BK];
  const int t = threadIdx.x;
  const int l = t & 63;
  const int w = t >> 6;
  const int wr = w / WC, wc = w % WC;
  const int lr = l & 15, lg = l >> 4;
  const int m0 = blockIdx.y * BM, n0 = blockIdx.x * BN;
  const int koff = blockIdx.z * kstep;
  A += koff; B += koff;
  Cf += (size_t)blockIdx.z * M * N;
  f32x4 acc[4][4] = {};
  for (int k0 = 0; k0 < K; k0 += BK) {
#pragma unroll
    for (int i = 0; i < AISS; ++i) {
      int e = (i * THREADS + t) * 8;
      int r = e >> 5, c = e & 31;
      gload_lds16(A + (size_t)(m0 + r) * lda + k0 + c, As + (size_t)(i * THREADS + w * 64) * 8);
    }
#pragma unroll
    for (int i = 0; i < BISS; ++i) {
      int e = (i * THREADS + t) * 8;
      int r = e >> 5, c = e & 31;
      gload_lds16(B + (size_t)(n0 + r) * ldb + k0 + c, Bs + (size_t)(i * THREADS + w * 64) * 8);
    }
    __syncthreads();
    short8 a[4], b[4];
#pragma unroll
    for (int m = 0; m < 4; ++m)
      a[m] = *(const short8*)(As + (wr * 64 + m * 16 + lr) * BK + lg * 8);
#pragma unroll
    for (int n = 0; n < 4; ++n)
      b[n] = *(const short8*)(Bs + (wc * 64 + n * 16 + lr) * BK + lg * 8);
#pragma unroll
    for (int m = 0; m < 4; ++m)
#pragma unroll
      for (int n = 0; n < 4; ++n)
        acc[m][n] = __builtin_amdgcn_mfma_f32_16x16x32_bf16(a[m], b[n], acc[m][n], 0, 0, 0);
    __syncthreads();
  }
#pragma unroll
  for (int n = 0; n < 4; ++n) {
    const int col = n0 + wc * 64 + n * 16 + lr;
    const float bv = BIAS ? bias[col] : 0.0f;
#pragma unroll
    for (int m = 0; m < 4; ++m) {
#pragma unroll
      for (int r = 0; r < 4; ++r) {
        const int row = m0 + wr * 64 + m * 16 + lg * 4 + r;
        float v = acc[m][n][r] + bv;
        if (RELU) v = fmaxf(v, 0.0f);
        if (BF16OUT) Cb[(size_t)row * N + col] = f2b(v);
        else         Cf[(size_t)row * N + col] = v;
      }
    }
  }
}

// ---------------- transpose V: qkvb[:,1024:2048] ([N][D]) -> vt [D][N] ----------------
__global__ void transpose_v(const short* __restrict__ src, short* __restrict__ dst) {
  __shared__ short tile[64][65];
  const int bx = blockIdx.x * 64;  // d
  const int by = blockIdx.y * 64;  // n
  const int t = threadIdx.x;
  const int tx = t & 63, ty = t >> 6;
#pragma unroll
  for (int i = 0; i < 64; i += 4)
    tile[ty + i][tx] = src[(size_t)(by + ty + i) * 2048 + 1024 + bx + tx];
  __syncthreads();
#pragma unroll
  for (int i = 0; i < 64; i += 4)
    dst[(size_t)(bx + ty + i) * 2048 + by + tx] = tile[tx][ty + i];
}

// ---------------- flash attention, KV-split: partial O + (m,l) stats ----------------
// grid (N/16, H, NSPLIT); 64 threads. Swapped QK^T: lane holds Q-row lr,
// K-positions n*16+lg*4+r. Tree reductions; P via wave-private LDS.
// po[z][row][1024], pml[z][h][row] = (m, l) unnormalized-softmax stats.
__launch_bounds__(64, 4)
__global__ void flash_attn(const short* __restrict__ qk, const short* __restrict__ vt,
                           float* __restrict__ po_base, float2* __restrict__ pml) {
  const int l = threadIdx.x & 63;
  const int lr = l & 15, lg = l >> 4;
  const int h = blockIdx.y;
  const int qb = blockIdx.x;
  const int z = blockIdx.z;
  __shared__ short Pl[16][72];
  const float C2 = 0.18033688011112042f;  // (1/sqrt(64)) * log2(e)
  const int KT = NTOK / 64 / NSPLIT;      // 8 K-tiles per split
  const int kt0 = z * KT;

  const short* kbase = qk + h * 64;
  const short* vbase = vt + (size_t)h * 64 * 2048;
  float* po = po_base + (size_t)z * NTOK * DMODEL;

  short8 aq[2];
  const int qrow = qb * 16 + lr;
#pragma unroll
  for (int f = 0; f < 2; ++f)
    aq[f] = *(const short8*)(qk + (size_t)qrow * 2048 + h * 64 + f * 32 + lg * 8);

  f32x4 o[4] = {};
  float mrun = -1e30f, lrun = 0.0f;

  short8 kA[2][4], kB[2][4];
#pragma unroll
  for (int f = 0; f < 2; ++f)
#pragma unroll
    for (int n = 0; n < 4; ++n)
      kA[f][n] = *(const short8*)(kbase + (size_t)(kt0 * 64 + n * 16 + lr) * 2048 + f * 32 + lg * 8);

  auto step = [&](int kt, short8 (&kc)[2][4], short8 (&kn)[2][4], bool pref) {
    f32x4 s[4] = {};
#pragma unroll
    for (int f = 0; f < 2; ++f)
#pragma unroll
      for (int n = 0; n < 4; ++n)
        s[n] = __builtin_amdgcn_mfma_f32_16x16x32_bf16(kc[f][n], aq[f], s[n], 0, 0, 0);
    short8 bv[2][4];
#pragma unroll
    for (int f = 0; f < 2; ++f)
#pragma unroll
      for (int n = 0; n < 4; ++n)
        bv[f][n] = *(const short8*)(vbase + (size_t)(n * 16 + lr) * 2048 + kt * 64 + f * 32 + lg * 8);
    if (pref) {
#pragma unroll
      for (int f = 0; f < 2; ++f)
#pragma unroll
        for (int n = 0; n < 4; ++n)
          kn[f][n] = *(const short8*)(kbase + (size_t)((kt + 1) * 64 + n * 16 + lr) * 2048 + f * 32 + lg * 8);
    }
    // row max: depth-4 tree + 2 shfl
    float m0 = fmaxf(fmaxf(s[0][0], s[0][1]), fmaxf(s[0][2], s[0][3]));
    float m1 = fmaxf(fmaxf(s[1][0], s[1][1]), fmaxf(s[1][2], s[1][3]));
    float m2 = fmaxf(fmaxf(s[2][0], s[2][1]), fmaxf(s[2][2], s[2][3]));
    float m3 = fmaxf(fmaxf(s[3][0], s[3][1]), fmaxf(s[3][2], s[3][3]));
    float tm = fmaxf(fmaxf(m0, m1), fmaxf(m2, m3));
    tm = fmaxf(tm, __shfl_xor(tm, 16));
    tm = fmaxf(tm, __shfl_xor(tm, 32));
    const float mnew = fmaxf(mrun, tm);
    const float corr = fexp2((mrun - mnew) * C2);
    mrun = mnew;
    float p[4][4];
#pragma unroll
    for (int n = 0; n < 4; ++n)
#pragma unroll
      for (int r = 0; r < 4; ++r)
        p[n][r] = fexp2((s[n][r] - mnew) * C2);
    // row sum: depth-4 tree + 2 shfl
    float q0 = (p[0][0] + p[0][1]) + (p[0][2] + p[0][3]);
    float q1 = (p[1][0] + p[1][1]) + (p[1][2] + p[1][3]);
    float q2 = (p[2][0] + p[2][1]) + (p[2][2] + p[2][3]);
    float q3 = (p[3][0] + p[3][1]) + (p[3][2] + p[3][3]);
    float ps = (q0 + q1) + (q2 + q3);
    ps += __shfl_xor(ps, 16);
    ps += __shfl_xor(ps, 32);
    lrun = lrun * corr + ps;
    // corr: P-layout (row=lr) -> O-layout (rows lg*4+r)
    f32x4 cov;
#pragma unroll
    for (int r = 0; r < 4; ++r)
      cov[r] = __shfl(corr, lg * 4 + r);
#pragma unroll
    for (int n = 0; n < 4; ++n)
      o[n] *= cov;
    // P -> LDS -> A-frag
#pragma unroll
    for (int n = 0; n < 4; ++n) {
      uint2 wv;
      wv.x = ((unsigned)(unsigned short)f2b(p[n][1]) << 16) | (unsigned short)f2b(p[n][0]);
      wv.y = ((unsigned)(unsigned short)f2b(p[n][3]) << 16) | (unsigned short)f2b(p[n][2]);
      *(uint2*)&Pl[lr][n * 16 + lg * 4] = wv;
    }
#pragma unroll
    for (int f = 0; f < 2; ++f) {
      short8 ap = *(const short8*)&Pl[lr][f * 32 + lg * 8];
#pragma unroll
      for (int n = 0; n < 4; ++n)
        o[n] = __builtin_amdgcn_mfma_f32_16x16x32_bf16(ap, bv[f][n], o[n], 0, 0, 0);
    }
  };

#pragma unroll 1
  for (int kt = kt0; kt < kt0 + KT; kt += 2) {
    step(kt, kA, kB, true);
    step(kt + 1, kB, kA, kt + 2 < kt0 + KT);
  }

  // unnormalized partial O + stats
#pragma unroll
  for (int n = 0; n < 4; ++n)
#pragma unroll
    for (int r = 0; r < 4; ++r)
      po[(size_t)(qb * 16 + lg * 4 + r) * 1024 + h * 64 + n * 16 + lr] = o[n][r];
  if (l < 16) {
    float2 st; st.x = mrun; st.y = lrun;
    pml[(size_t)(z * NHEAD + h) * NTOK + qb * 16 + l] = st;
  }
}

// ---------------- merge partials + residual + LN1 -> h (f32) + hb (bf16) ----------------
__launch_bounds__(256)
__global__ void merge_ln(const float* __restrict__ X, const float* __restrict__ po,
                         const float2* __restrict__ pml,
                         const float* __restrict__ g, const float* __restrict__ be,
                         float* __restrict__ outf, short* __restrict__ outb) {
  const int row = blockIdx.x;
  const int t = threadIdx.x;
  const int head = t >> 4;
  const float C2 = 0.18033688011112042f;
  // stats for this (row, head)
  float m[NSPLIT], lv[NSPLIT];
#pragma unroll
  for (int s = 0; s < NSPLIT; ++s) {
    float2 st = pml[(size_t)(s * NHEAD + head) * NTOK + row];
    m[s] = st.x; lv[s] = st.y;
  }
  float M = fmaxf(fmaxf(m[0], m[1]), fmaxf(m[2], m[3]));
  float wgt[NSPLIT], L = 0.0f;
#pragma unroll
  for (int s = 0; s < NSPLIT; ++s) {
    wgt[s] = fexp2((m[s] - M) * C2);
    L += wgt[s] * lv[s];
  }
  const float invL = 1.0f / L;
  const size_t base = (size_t)row * 1024 + t * 4;
  f32x4 acc = {};
#pragma unroll
  for (int s = 0; s < NSPLIT; ++s) {
    float4 v = *(const float4*)(po + (size_t)s * NTOK * DMODEL + base);
    acc[0] += wgt[s] * v.x; acc[1] += wgt[s] * v.y;
    acc[2] += wgt[s] * v.z; acc[3] += wgt[s] * v.w;
  }
  float4 a = *(const float4*)(X + base);
  float4 sv;
  sv.x = a.x + acc[0] * invL; sv.y = a.y + acc[1] * invL;
  sv.z = a.z + acc[2] * invL; sv.w = a.w + acc[3] * invL;
  float sum = sv.x + sv.y + sv.z + sv.w;
  float sq  = sv.x * sv.x + sv.y * sv.y + sv.z * sv.z + sv.w * sv.w;
#pragma unroll
  for (int d = 32; d > 0; d >>= 1) {
    sum += __shfl_down(sum, d);
    sq  += __shfl_down(sq, d);
  }
  __shared__ float red[8];
  const int w = t >> 6, l = t & 63;
  if (l == 0) { red[w] = sum; red[4 + w] = sq; }
  __syncthreads();
  sum = red[0] + red[1] + red[2] + red[3];
  sq  = red[4] + red[5] + red[6] + red[7];
  const float mu = sum * (1.0f / 1024.0f);
  const float rstd = rsqrtf(sq * (1.0f / 1024.0f) - mu * mu + 1e-5f);
  float4 gv = *(const float4*)(g + t * 4);
  float4 bvv = *(const float4*)(be + t * 4);
  float4 ov;
  ov.x = (sv.x - mu) * rstd * gv.x + bvv.x;
  ov.y = (sv.y - mu) * rstd * gv.y + bvv.y;
  ov.z = (sv.z - mu) * rstd * gv.z + bvv.z;
  ov.w = (sv.w - mu) * rstd * gv.w + bvv.w;
  *(float4*)(outf + base) = ov;
  short4v ob; ob.x = f2b(ov.x); ob.y = f2b(ov.y); ob.z = f2b(ov.z); ob.w = f2b(ov.w);
  *(short4v*)(outb + base) = ob;
}

// ---------------- out = LN(A + B0 [+ B1] [+ bias]) * g + be ----------------
__launch_bounds__(256)
__global__ void add_ln(const float* __restrict__ A, const float* __restrict__ B0,
                       const float* __restrict__ B1, const float* __restrict__ bias,
                       const float* __restrict__ g, const float* __restrict__ be,
                       float* __restrict__ outf, short* __restrict__ outb) {
  const int row = blockIdx.x;
  const int t = threadIdx.x;
  const size_t base = (size_t)row * 1024 + t * 4;
  float4 a = *(const float4*)(A + base);
  float4 b = *(const float4*)(B0 + base);
  float4 s; s.x = a.x + b.x; s.y = a.y + b.y; s.z = a.z + b.z; s.w = a.w + b.w;
  if (B1) {
    float4 c = *(const float4*)(B1 + base);
    s.x += c.x; s.y += c.y; s.z += c.z; s.w += c.w;
  }
  if (bias) {
    float4 c = *(const float4*)(bias + t * 4);
    s.x += c.x; s.y += c.y; s.z += c.z; s.w += c.w;
  }
  float sum = s.x + s.y + s.z + s.w;
  float sq  = s.x * s.x + s.y * s.y + s.z * s.z + s.w * s.w;
#pragma unroll
  for (int d = 32; d > 0; d >>= 1) {
    sum += __shfl_down(sum, d);
    sq  += __shfl_down(sq, d);
  }
  __shared__ float red[8];
  const int w = t >> 6, l = t & 63;
  if (l == 0) { red[w] = sum; red[4 + w] = sq; }
  __syncthreads();
  sum = red[0] + red[1] + red[2] + red[3];
  sq  = red[4] + red[5] + red[6] + red[7];
  const float mu = sum * (1.0f / 1024.0f);
  const float rstd = rsqrtf(sq * (1.0f / 1024.0f) - mu * mu + 1e-5f);
  float4 gv = *(const float4*)(g + t * 4);
  float4 bv = *(const float4*)(be + t * 4);
  float4 o;
  o.x = (s.x - mu) * rstd * gv.x + bv.x;
  o.y = (s.y - mu) * rstd * gv.y + bv.y;
  o.z = (s.z - mu) * rstd * gv.z + bv.z;
  o.w = (s.w - mu) * rstd * gv.w + bv.w;
  *(float4*)(outf + base) = o;
  if (outb) {
    short4v ob; ob.x = f2b(o.x); ob.y = f2b(o.y); ob.z = f2b(o.z); ob.w = f2b(o.w);
    *(short4v*)(outb + base) = ob;
  }
}

extern "C" void kernel_launch(void* const* d_in, const int* in_sizes, int n_in,
                              void* d_out, int out_size, void* d_ws, size_t ws_size,
                              hipStream_t stream) {
  const float* X    = (const float*)d_in[0];
  const float* Wqkv = (const float*)d_in[1];
  const float* W1   = (const float*)d_in[2];
  const float* b1   = (const float*)d_in[3];
  const float* W2   = (const float*)d_in[4];
  const float* b2   = (const float*)d_in[5];
  const float* g1   = (const float*)d_in[6];
  const float* be1  = (const float*)d_in[7];
  const float* g2   = (const float*)d_in[8];
  const float* be2  = (const float*)d_in[9];

  // workspace layout, explicit offsets (68 MiB total). Live ranges:
  //  [0,8)M   W1b      cast -> FFN1
  //  [8,16)M  W2b      cast -> FFN2
  //  [16,24)M qkvb     QKVgemm -> flash     | then h (f32)   merge_ln -> LN2
  //  [24,28)M vt       transpose -> flash   | then hb (bf16) merge_ln -> FFN1
  //  [28,32)M Xb       cast -> QKVgemm      | then pml [28,29)M flash -> merge_ln
  //  [32,36)M Wqkvb    cast -> QKVgemm
  //  [36,68)M po[4]    flash -> merge_ln    | then y1b [36,52)M, P0/P1 [52,68)M
  char* ws = (char*)d_ws;
  const size_t MiB = 1u << 20;
  short*  W1b   = (short*)(ws + 0 * MiB);
  short*  W2b   = (short*)(ws + 8 * MiB);
  short*  qkvb  = (short*)(ws + 16 * MiB);
  short*  vt    = (short*)(ws + 24 * MiB);
  short*  Xb    = (short*)(ws + 28 * MiB);
  short*  Wqkvb = (short*)(ws + 32 * MiB);
  float*  po    = (float*)(ws + 36 * MiB);
  float2* pml   = (float2*)(ws + 28 * MiB);
  float*  h     = (float*)(ws + 16 * MiB);
  short*  hb    = (short*)(ws + 24 * MiB);
  short*  y1b   = (short*)(ws + 36 * MiB);
  float*  P0    = (float*)(ws + 52 * MiB);
  float*  P1    = P0 + (size_t)NTOK * DMODEL;

  cast_all<<<6144, 256, 0, stream>>>(X, Xb, NTOK * DMODEL / 8,
                                     Wqkv, Wqkvb, 2 * DMODEL * DMODEL / 8,
                                     W1, W1b, DFF * DMODEL / 8,
                                     W2, W2b, DMODEL * DFF / 8);

  {  // qkv = X @ Wqkv^T -> bf16 [2048, 2048]
    dim3 grid(2 * DMODEL / 128, NTOK / 128, 1);
    gemm_bt<128, 128, 2, 2, true, false, false><<<grid, 256, 0, stream>>>(
        Xb, Wqkvb, nullptr, nullptr, qkvb, NTOK, 2 * DMODEL, DMODEL, DMODEL, DMODEL, 0);
  }
  {  // vt[d][n] = v[n][d]
    dim3 grid(DMODEL / 64, NTOK / 64);
    transpose_v<<<grid, 256, 0, stream>>>(qkvb, vt);
  }
  {  // partial attention, KV-split x4
    dim3 grid(NTOK / 16, NHEAD, NSPLIT);
    flash_attn<<<grid, 64, 0, stream>>>(qkvb, vt, po, pml);
  }
  // merge partials + residual + LN1
  merge_ln<<<NTOK, 256, 0, stream>>>(X, po, pml, g1, be1, h, hb);
  {  // y1 = relu(h @ W1^T + b1) -> bf16 [2048, 4096]
    dim3 grid(DFF / 128, NTOK / 128, 1);
    gemm_bt<128, 128, 2, 2, true, true, true><<<grid, 256, 0, stream>>>(
        hb, W1b, b1, nullptr, y1b, NTOK, DFF, DMODEL, DMODEL, DMODEL, 0);
  }
  {  // ffn2 partials: split-K=2; bias b2 folded into LN2
    dim3 grid(DMODEL / 128, NTOK / 128, 2);
    gemm_bt<128, 128, 2, 2, false, false, false><<<grid, 256, 0, stream>>>(
        y1b, W2b, nullptr, P0, nullptr, NTOK, DMODEL, 2048, DFF, DFF, 2048);
  }
  add_ln<<<NTOK, 256, 0, stream>>>(h, P0, P1, b2, g2, be2, (float*)d_out, nullptr);
}

// Round 6
// 276.961 us; speedup vs baseline: 1.2891x; 1.2891x over previous
//
#include <hip/hip_runtime.h>
#include <stdint.h>

// TransformerBlock on MI355X (gfx950), bf16-MFMA. Round 6.
// vs R5: KV-split removed (merge traffic cost > benefit; occupancy was not the
// limiter). flash_attn now stages K/V tiles in LDS via coalesced global_load_lds
// (1KB fully-used per instr vs 16 scattered 64B lines), double-buffered, shared
// across 4 waves; fragment reads from LDS with XOR chunk swizzle (both-sides).

#define NTOK 2048
#define DMODEL 1024
#define NHEAD 16
#define DHEAD 64
#define DFF 4096

typedef __attribute__((ext_vector_type(8))) short short8;
typedef __attribute__((ext_vector_type(4))) short short4v;
typedef __attribute__((ext_vector_type(4))) float f32x4;

__device__ __forceinline__ float fexp2(float x) { return __builtin_amdgcn_exp2f(x); }

// fp32 -> bf16 RNE
__device__ __forceinline__ short f2b(float f) {
  union { float f; unsigned u; } v; v.f = f;
  unsigned r = v.u + 0x7fffu + ((v.u >> 16) & 1u);
  return (short)(r >> 16);
}

__device__ __forceinline__ void gload_lds16(const void* g, void* l) {
  __builtin_amdgcn_global_load_lds((const __attribute__((address_space(1))) void*)g,
                                   (__attribute__((address_space(3))) void*)l,
                                   16, 0, 0);
}

// ---------------- fused cast fp32 -> bf16 for 4 tensors ----------------
__global__ void cast_all(const float* __restrict__ s0, short* __restrict__ d0, int n0,
                         const float* __restrict__ s1, short* __restrict__ d1, int n1,
                         const float* __restrict__ s2, short* __restrict__ d2, int n2,
                         const float* __restrict__ s3, short* __restrict__ d3, int n3) {
  int i = blockIdx.x * blockDim.x + threadIdx.x;
  const float* s; short* d; int j = i;
  if (j < n0) { s = s0; d = d0; }
  else { j -= n0;
    if (j < n1) { s = s1; d = d1; }
    else { j -= n1;
      if (j < n2) { s = s2; d = d2; }
      else { j -= n2; if (j >= n3) return; s = s3; d = d3; }
    }
  }
  const float4* p = (const float4*)(s + (size_t)j * 8);
  float4 a = p[0], b = p[1];
  short8 o;
  o[0] = f2b(a.x); o[1] = f2b(a.y); o[2] = f2b(a.z); o[3] = f2b(a.w);
  o[4] = f2b(b.x); o[5] = f2b(b.y); o[6] = f2b(b.z); o[7] = f2b(b.w);
  *(short8*)(d + (size_t)j * 8) = o;
}

// ---------------- GEMM: C = A @ B^T (+relu/bias), bf16 in, f32 acc ----------------
template<int BM, int BN, int WR, int WC, bool BF16OUT, bool BIAS, bool RELU>
__launch_bounds__(WR * WC * 64)
__global__ void gemm_bt(const short* __restrict__ A, const short* __restrict__ B,
                        const float* __restrict__ bias,
                        float* __restrict__ Cf, short* __restrict__ Cb,
                        int M, int N, int K, int lda, int ldb, int kstep) {
  constexpr int BK = 32;
  constexpr int THREADS = WR * WC * 64;
  constexpr int AISS = (BM * BK) / (8 * THREADS);
  constexpr int BISS = (BN * BK) / (8 * THREADS);
  __shared__ short As[BM * BK];
  __shared__ short Bs[BN * BK];
  const int t = threadIdx.x;
  const int l = t & 63;
  const int w = t >> 6;
  const int wr = w / WC, wc = w % WC;
  const int lr = l & 15, lg = l >> 4;
  const int m0 = blockIdx.y * BM, n0 = blockIdx.x * BN;
  const int koff = blockIdx.z * kstep;
  A += koff; B += koff;
  Cf += (size_t)blockIdx.z * M * N;
  f32x4 acc[4][4] = {};
  for (int k0 = 0; k0 < K; k0 += BK) {
#pragma unroll
    for (int i = 0; i < AISS; ++i) {
      int e = (i * THREADS + t) * 8;
      int r = e >> 5, c = e & 31;
      gload_lds16(A + (size_t)(m0 + r) * lda + k0 + c, As + (size_t)(i * THREADS + w * 64) * 8);
    }
#pragma unroll
    for (int i = 0; i < BISS; ++i) {
      int e = (i * THREADS + t) * 8;
      int r = e >> 5, c = e & 31;
      gload_lds16(B + (size_t)(n0 + r) * ldb + k0 + c, Bs + (size_t)(i * THREADS + w * 64) * 8);
    }
    __syncthreads();
    short8 a[4], b[4];
#pragma unroll
    for (int m = 0; m < 4; ++m)
      a[m] = *(const short8*)(As + (wr * 64 + m * 16 + lr) * BK + lg * 8);
#pragma unroll
    for (int n = 0; n < 4; ++n)
      b[n] = *(const short8*)(Bs + (wc * 64 + n * 16 + lr) * BK + lg * 8);
#pragma unroll
    for (int m = 0; m < 4; ++m)
#pragma unroll
      for (int n = 0; n < 4; ++n)
        acc[m][n] = __builtin_amdgcn_mfma_f32_16x16x32_bf16(a[m], b[n], acc[m][n], 0, 0, 0);
    __syncthreads();
  }
#pragma unroll
  for (int n = 0; n < 4; ++n) {
    const int col = n0 + wc * 64 + n * 16 + lr;
    const float bv = BIAS ? bias[col] : 0.0f;
#pragma unroll
    for (int m = 0; m < 4; ++m) {
#pragma unroll
      for (int r = 0; r < 4; ++r) {
        const int row = m0 + wr * 64 + m * 16 + lg * 4 + r;
        float v = acc[m][n][r] + bv;
        if (RELU) v = fmaxf(v, 0.0f);
        if (BF16OUT) Cb[(size_t)row * N + col] = f2b(v);
        else         Cf[(size_t)row * N + col] = v;
      }
    }
  }
}

// ---------------- transpose V: qkvb[:,1024:2048] ([N][D]) -> vt [D][N] ----------------
__global__ void transpose_v(const short* __restrict__ src, short* __restrict__ dst) {
  __shared__ short tile[64][65];
  const int bx = blockIdx.x * 64;  // d
  const int by = blockIdx.y * 64;  // n
  const int t = threadIdx.x;
  const int tx = t & 63, ty = t >> 6;
#pragma unroll
  for (int i = 0; i < 64; i += 4)
    tile[ty + i][tx] = src[(size_t)(by + ty + i) * 2048 + 1024 + bx + tx];
  __syncthreads();
#pragma unroll
  for (int i = 0; i < 64; i += 4)
    dst[(size_t)(bx + ty + i) * 2048 + by + tx] = tile[tx][ty + i];
}

// ---------------- flash attention, LDS-staged K/V, 4 waves/block ----------------
// grid (N/64, H); 256 threads. Wave w owns Q rows qb*64+w*16..+16.
// K tile [64 rows][64 d] and V tile [64 d][64 n] (from vt) staged in LDS as
// 8 chunks/row of 16B with XOR swizzle: LDS slot (r, c) holds global chunk
// (r, c ^ (r&7)); gload_lds dest stays linear, source pre-swizzled (m201 rule).
// Read of chunk (r, cc) = LDS (r, cc ^ (r&7)) -> 64-lane b128 reads spread over
// all 8 16B bank-groups (conflict-free vs 2-way unswizzled).
// Double-buffered: stage tile kt+1 before computing kt; __syncthreads drains.
__launch_bounds__(256, 2)
__global__ void flash_attn(const short* __restrict__ qk, const short* __restrict__ vt,
                           float* __restrict__ O) {
  const int t = threadIdx.x;
  const int l = t & 63, w = t >> 6;
  const int lr = l & 15, lg = l >> 4;
  const int h = blockIdx.y;
  const int qb = blockIdx.x;
  __shared__ short Ks[2][64 * 64];
  __shared__ short Vs[2][64 * 64];
  __shared__ short Pl[4][16][72];
  const float C2 = 0.18033688011112042f;  // (1/sqrt(64)) * log2(e)

  // Q fragments (one-time, 16 rows per wave)
  const int qrow = qb * 64 + w * 16 + lr;
  short8 aq[2];
#pragma unroll
  for (int f = 0; f < 2; ++f)
    aq[f] = *(const short8*)(qk + (size_t)qrow * 2048 + h * 64 + f * 32 + lg * 8);

  f32x4 o[4] = {};
  float mrun = -1e30f, lrun = 0.0f;

  // stage tile kt into buffer b: whole block, 2 instrs/tensor/thread-wave
  auto stage = [&](int b, int kt) {
#pragma unroll
    for (int i = 0; i < 2; ++i) {
      const int chunk = i * 256 + w * 64 + l;         // 0..511
      const int r = chunk >> 3, c = chunk & 7;        // row 0..63, chunk col 0..7
      const int cs = c ^ (r & 7);                     // inverse-swizzled source col
      gload_lds16(qk + (size_t)(kt * 64 + r) * 2048 + h * 64 + cs * 8,
                  &Ks[b][(size_t)(i * 256 + w * 64) * 8]);
    }
#pragma unroll
    for (int i = 0; i < 2; ++i) {
      const int chunk = i * 256 + w * 64 + l;
      const int r = chunk >> 3, c = chunk & 7;
      const int cs = c ^ (r & 7);
      gload_lds16(vt + (size_t)(h * 64 + r) * 2048 + kt * 64 + cs * 8,
                  &Vs[b][(size_t)(i * 256 + w * 64) * 8]);
    }
  };

  stage(0, 0);
  __syncthreads();

#pragma unroll 1
  for (int kt = 0; kt < 32; ++kt) {
    const int cur = kt & 1;
    if (kt + 1 < 32) stage(cur ^ 1, kt + 1);  // async prefetch overlaps compute

    // QK^T (swapped): A = K rows (n*16+lr), B = Q; lane holds Q-row lr,
    // K-positions n*16+lg*4+r in C layout.
    f32x4 s[4] = {};
#pragma unroll
    for (int f = 0; f < 2; ++f) {
      short8 kf[4];
#pragma unroll
      for (int n = 0; n < 4; ++n) {
        const int r = n * 16 + lr;
        kf[n] = *(const short8*)(&Ks[cur][r * 64 + (((f * 4 + lg) ^ (lr & 7)) * 8)]);
      }
#pragma unroll
      for (int n = 0; n < 4; ++n)
        s[n] = __builtin_amdgcn_mfma_f32_16x16x32_bf16(kf[n], aq[f], s[n], 0, 0, 0);
    }
    // row max: depth-4 tree + 2 shfl
    float m0 = fmaxf(fmaxf(s[0][0], s[0][1]), fmaxf(s[0][2], s[0][3]));
    float m1 = fmaxf(fmaxf(s[1][0], s[1][1]), fmaxf(s[1][2], s[1][3]));
    float m2 = fmaxf(fmaxf(s[2][0], s[2][1]), fmaxf(s[2][2], s[2][3]));
    float m3 = fmaxf(fmaxf(s[3][0], s[3][1]), fmaxf(s[3][2], s[3][3]));
    float tm = fmaxf(fmaxf(m0, m1), fmaxf(m2, m3));
    tm = fmaxf(tm, __shfl_xor(tm, 16));
    tm = fmaxf(tm, __shfl_xor(tm, 32));
    const float mnew = fmaxf(mrun, tm);
    const float corr = fexp2((mrun - mnew) * C2);
    mrun = mnew;
    float p[4][4];
#pragma unroll
    for (int n = 0; n < 4; ++n)
#pragma unroll
      for (int r = 0; r < 4; ++r)
        p[n][r] = fexp2((s[n][r] - mnew) * C2);
    float q0 = (p[0][0] + p[0][1]) + (p[0][2] + p[0][3]);
    float q1 = (p[1][0] + p[1][1]) + (p[1][2] + p[1][3]);
    float q2 = (p[2][0] + p[2][1]) + (p[2][2] + p[2][3]);
    float q3 = (p[3][0] + p[3][1]) + (p[3][2] + p[3][3]);
    float ps = (q0 + q1) + (q2 + q3);
    ps += __shfl_xor(ps, 16);
    ps += __shfl_xor(ps, 32);
    lrun = lrun * corr + ps;
    // corr: P-layout (row = lr) -> O-layout (rows lg*4+r)
    f32x4 cov;
#pragma unroll
    for (int r = 0; r < 4; ++r)
      cov[r] = __shfl(corr, lg * 4 + r);
#pragma unroll
    for (int n = 0; n < 4; ++n)
      o[n] *= cov;
    // P -> LDS (wave-private) -> A-frag
#pragma unroll
    for (int n = 0; n < 4; ++n) {
      uint2 wv;
      wv.x = ((unsigned)(unsigned short)f2b(p[n][1]) << 16) | (unsigned short)f2b(p[n][0]);
      wv.y = ((unsigned)(unsigned short)f2b(p[n][3]) << 16) | (unsigned short)f2b(p[n][2]);
      *(uint2*)&Pl[w][lr][n * 16 + lg * 4] = wv;
    }
    // PV: A = P (rows = Q-rows lr), B = V from LDS (rows = d-pos n*16+lr)
#pragma unroll
    for (int f = 0; f < 2; ++f) {
      short8 ap = *(const short8*)&Pl[w][lr][f * 32 + lg * 8];
      short8 vf[4];
#pragma unroll
      for (int n = 0; n < 4; ++n) {
        const int r = n * 16 + lr;
        vf[n] = *(const short8*)(&Vs[cur][r * 64 + (((f * 4 + lg) ^ (lr & 7)) * 8)]);
      }
#pragma unroll
      for (int n = 0; n < 4; ++n)
        o[n] = __builtin_amdgcn_mfma_f32_16x16x32_bf16(ap, vf[n], o[n], 0, 0, 0);
    }
    __syncthreads();  // drains prefetch (next buf ready) + protects cur for overwrite
  }

  // normalize: lrun lives per-lane for row lr; redistribute to O-layout rows lg*4+r
  f32x4 inv;
#pragma unroll
  for (int r = 0; r < 4; ++r)
    inv[r] = 1.0f / __shfl(lrun, lg * 4 + r);
#pragma unroll
  for (int n = 0; n < 4; ++n)
#pragma unroll
    for (int r = 0; r < 4; ++r)
      O[(size_t)(qb * 64 + w * 16 + lg * 4 + r) * 1024 + h * 64 + n * 16 + lr] = o[n][r] * inv[r];
}

// ---------------- out = LN(A + B0 [+ B1] [+ bias]) * g + be ----------------
__launch_bounds__(256)
__global__ void add_ln(const float* __restrict__ A, const float* __restrict__ B0,
                       const float* __restrict__ B1, const float* __restrict__ bias,
                       const float* __restrict__ g, const float* __restrict__ be,
                       float* __restrict__ outf, short* __restrict__ outb) {
  const int row = blockIdx.x;
  const int t = threadIdx.x;
  const size_t base = (size_t)row * 1024 + t * 4;
  float4 a = *(const float4*)(A + base);
  float4 b = *(const float4*)(B0 + base);
  float4 s; s.x = a.x + b.x; s.y = a.y + b.y; s.z = a.z + b.z; s.w = a.w + b.w;
  if (B1) {
    float4 c = *(const float4*)(B1 + base);
    s.x += c.x; s.y += c.y; s.z += c.z; s.w += c.w;
  }
  if (bias) {
    float4 c = *(const float4*)(bias + t * 4);
    s.x += c.x; s.y += c.y; s.z += c.z; s.w += c.w;
  }
  float sum = s.x + s.y + s.z + s.w;
  float sq  = s.x * s.x + s.y * s.y + s.z * s.z + s.w * s.w;
#pragma unroll
  for (int d = 32; d > 0; d >>= 1) {
    sum += __shfl_down(sum, d);
    sq  += __shfl_down(sq, d);
  }
  __shared__ float red[8];
  const int w = t >> 6, l = t & 63;
  if (l == 0) { red[w] = sum; red[4 + w] = sq; }
  __syncthreads();
  sum = red[0] + red[1] + red[2] + red[3];
  sq  = red[4] + red[5] + red[6] + red[7];
  const float mu = sum * (1.0f / 1024.0f);
  const float rstd = rsqrtf(sq * (1.0f / 1024.0f) - mu * mu + 1e-5f);
  float4 gv = *(const float4*)(g + t * 4);
  float4 bv = *(const float4*)(be + t * 4);
  float4 o;
  o.x = (s.x - mu) * rstd * gv.x + bv.x;
  o.y = (s.y - mu) * rstd * gv.y + bv.y;
  o.z = (s.z - mu) * rstd * gv.z + bv.z;
  o.w = (s.w - mu) * rstd * gv.w + bv.w;
  *(float4*)(outf + base) = o;
  if (outb) {
    short4v ob; ob.x = f2b(o.x); ob.y = f2b(o.y); ob.z = f2b(o.z); ob.w = f2b(o.w);
    *(short4v*)(outb + base) = ob;
  }
}

extern "C" void kernel_launch(void* const* d_in, const int* in_sizes, int n_in,
                              void* d_out, int out_size, void* d_ws, size_t ws_size,
                              hipStream_t stream) {
  const float* X    = (const float*)d_in[0];
  const float* Wqkv = (const float*)d_in[1];
  const float* W1   = (const float*)d_in[2];
  const float* b1   = (const float*)d_in[3];
  const float* W2   = (const float*)d_in[4];
  const float* b2   = (const float*)d_in[5];
  const float* g1   = (const float*)d_in[6];
  const float* be1  = (const float*)d_in[7];
  const float* g2   = (const float*)d_in[8];
  const float* be2  = (const float*)d_in[9];

  // workspace layout, explicit offsets (68 MiB). Live ranges:
  //  [0,8)M   W1b    cast -> FFN1
  //  [8,16)M  W2b    cast -> FFN2
  //  [16,24)M qkvb   QKVgemm -> flash   | then y1b [16,32)M  FFN1 -> FFN2
  //  [24,28)M vt     transpose -> flash |
  //  [28,32)M Xb     cast -> QKVgemm    |
  //  [32,36)M Wqkvb  cast -> QKVgemm
  //  [36,44)M attn   flash -> LN1
  //  [44,52)M h      LN1 -> final LN
  //  [52,56)M hb     LN1 -> FFN1        | then P0/P1 [52,68)M FFN2 -> LN2
  char* ws = (char*)d_ws;
  const size_t MiB = 1u << 20;
  short*  W1b   = (short*)(ws + 0 * MiB);
  short*  W2b   = (short*)(ws + 8 * MiB);
  short*  qkvb  = (short*)(ws + 16 * MiB);
  short*  vt    = (short*)(ws + 24 * MiB);
  short*  Xb    = (short*)(ws + 28 * MiB);
  short*  Wqkvb = (short*)(ws + 32 * MiB);
  float*  attn  = (float*)(ws + 36 * MiB);
  float*  h     = (float*)(ws + 44 * MiB);
  short*  hb    = (short*)(ws + 52 * MiB);
  short*  y1b   = (short*)(ws + 16 * MiB);
  float*  P0    = (float*)(ws + 52 * MiB);
  float*  P1    = P0 + (size_t)NTOK * DMODEL;

  cast_all<<<6144, 256, 0, stream>>>(X, Xb, NTOK * DMODEL / 8,
                                     Wqkv, Wqkvb, 2 * DMODEL * DMODEL / 8,
                                     W1, W1b, DFF * DMODEL / 8,
                                     W2, W2b, DMODEL * DFF / 8);

  {  // qkv = X @ Wqkv^T -> bf16 [2048, 2048]
    dim3 grid(2 * DMODEL / 128, NTOK / 128, 1);
    gemm_bt<128, 128, 2, 2, true, false, false><<<grid, 256, 0, stream>>>(
        Xb, Wqkvb, nullptr, nullptr, qkvb, NTOK, 2 * DMODEL, DMODEL, DMODEL, DMODEL, 0);
  }
  {  // vt[d][n] = v[n][d]
    dim3 grid(DMODEL / 64, NTOK / 64);
    transpose_v<<<grid, 256, 0, stream>>>(qkvb, vt);
  }
  {  // attn_out f32 [2048, 1024]; 4-wave blocks, LDS-staged K/V
    dim3 grid(NTOK / 64, NHEAD);
    flash_attn<<<grid, 256, 0, stream>>>(qkvb, vt, attn);
  }
  add_ln<<<NTOK, 256, 0, stream>>>(X, attn, nullptr, nullptr, g1, be1, h, hb);
  {  // y1 = relu(h @ W1^T + b1) -> bf16 [2048, 4096]
    dim3 grid(DFF / 128, NTOK / 128, 1);
    gemm_bt<128, 128, 2, 2, true, true, true><<<grid, 256, 0, stream>>>(
        hb, W1b, b1, nullptr, y1b, NTOK, DFF, DMODEL, DMODEL, DMODEL, 0);
  }
  {  // ffn2 partials: split-K=2; bias b2 folded into LN2
    dim3 grid(DMODEL / 128, NTOK / 128, 2);
    gemm_bt<128, 128, 2, 2, false, false, false><<<grid, 256, 0, stream>>>(
        y1b, W2b, nullptr, P0, nullptr, NTOK, DMODEL, 2048, DFF, DFF, 2048);
  }
  add_ln<<<NTOK, 256, 0, stream>>>(h, P0, P1, b2, g2, be2, (float*)d_out, nullptr);
}

// Round 7
// 251.133 us; speedup vs baseline: 1.4216x; 1.1028x over previous
//
#include <hip/hip_runtime.h>
#include <stdint.h>

// TransformerBlock on MI355X (gfx950), bf16-MFMA. Round 7.
// vs R6: gemm_bt rebuilt with the flash-proven pipeline — BK=64, explicit LDS
// double-buffer, stage(next)-async -> compute(cur) -> single barrier per iter
// (drain overlaps compute), XOR chunk-swizzle both-sides (16-way conflict fix
// at 128B row stride). Workspace re-laid out (60 MiB peak). Flash unchanged.

#define NTOK 2048
#define DMODEL 1024
#define NHEAD 16
#define DHEAD 64
#define DFF 4096

typedef __attribute__((ext_vector_type(8))) short short8;
typedef __attribute__((ext_vector_type(4))) short short4v;
typedef __attribute__((ext_vector_type(4))) float f32x4;

__device__ __forceinline__ float fexp2(float x) { return __builtin_amdgcn_exp2f(x); }

// fp32 -> bf16 RNE
__device__ __forceinline__ short f2b(float f) {
  union { float f; unsigned u; } v; v.f = f;
  unsigned r = v.u + 0x7fffu + ((v.u >> 16) & 1u);
  return (short)(r >> 16);
}

__device__ __forceinline__ void gload_lds16(const void* g, void* l) {
  __builtin_amdgcn_global_load_lds((const __attribute__((address_space(1))) void*)g,
                                   (__attribute__((address_space(3))) void*)l,
                                   16, 0, 0);
}

// ---------------- fused cast fp32 -> bf16 for 4 tensors ----------------
__global__ void cast_all(const float* __restrict__ s0, short* __restrict__ d0, int n0,
                         const float* __restrict__ s1, short* __restrict__ d1, int n1,
                         const float* __restrict__ s2, short* __restrict__ d2, int n2,
                         const float* __restrict__ s3, short* __restrict__ d3, int n3) {
  int i = blockIdx.x * blockDim.x + threadIdx.x;
  const float* s; short* d; int j = i;
  if (j < n0) { s = s0; d = d0; }
  else { j -= n0;
    if (j < n1) { s = s1; d = d1; }
    else { j -= n1;
      if (j < n2) { s = s2; d = d2; }
      else { j -= n2; if (j >= n3) return; s = s3; d = d3; }
    }
  }
  const float4* p = (const float4*)(s + (size_t)j * 8);
  float4 a = p[0], b = p[1];
  short8 o;
  o[0] = f2b(a.x); o[1] = f2b(a.y); o[2] = f2b(a.z); o[3] = f2b(a.w);
  o[4] = f2b(b.x); o[5] = f2b(b.y); o[6] = f2b(b.z); o[7] = f2b(b.w);
  *(short8*)(d + (size_t)j * 8) = o;
}

// ---------------- GEMM: C = A @ B^T (+relu/bias), bf16 in, f32 acc ----------------
// BK=64, LDS double-buffered, 1 barrier/iter (stage-next -> compute-cur -> sync).
// LDS layout: [row][8 chunks of 16B], slot (r,c) holds global chunk (r, c^(r&7)).
// gload_lds dest linear; source pre-swizzled; reads apply the same XOR (rule 21).
template<int BM, int BN, int WR, int WC, bool BF16OUT, bool BIAS, bool RELU>
__launch_bounds__(WR * WC * 64)
__global__ void gemm_bt(const short* __restrict__ A, const short* __restrict__ B,
                        const float* __restrict__ bias,
                        float* __restrict__ Cf, short* __restrict__ Cb,
                        int M, int N, int K, int lda, int ldb, int kstep) {
  constexpr int BK = 64;
  constexpr int THREADS = WR * WC * 64;
  constexpr int ACH = (BM * (BK / 8)) / THREADS;  // staging rounds for A
  constexpr int BCH = (BN * (BK / 8)) / THREADS;
  __shared__ short As[2][BM * BK];
  __shared__ short Bs[2][BN * BK];
  const int t = threadIdx.x;
  const int l = t & 63;
  const int w = t >> 6;
  const int wr = w / WC, wc = w % WC;
  const int lr = l & 15, lg = l >> 4;
  const int m0 = blockIdx.y * BM, n0 = blockIdx.x * BN;
  const int koff = blockIdx.z * kstep;
  A += koff; B += koff;
  Cf += (size_t)blockIdx.z * M * N;

  auto stage = [&](int b, int k0) {
#pragma unroll
    for (int i = 0; i < ACH; ++i) {
      const int ci = i * THREADS + t;           // chunk 0..BM*8-1
      const int r = ci >> 3, c = ci & 7;
      const int cs = c ^ (r & 7);               // inverse-swizzled source chunk
      gload_lds16(A + (size_t)(m0 + r) * lda + k0 + cs * 8,
                  &As[b][(size_t)(i * THREADS + w * 64) * 8]);
    }
#pragma unroll
    for (int i = 0; i < BCH; ++i) {
      const int ci = i * THREADS + t;
      const int r = ci >> 3, c = ci & 7;
      const int cs = c ^ (r & 7);
      gload_lds16(B + (size_t)(n0 + r) * ldb + k0 + cs * 8,
                  &Bs[b][(size_t)(i * THREADS + w * 64) * 8]);
    }
  };

  f32x4 acc[4][4] = {};
  const int nIter = K / BK;
  stage(0, 0);
  __syncthreads();
  for (int it = 0; it < nIter; ++it) {
    const int cur = it & 1;
    if (it + 1 < nIter) stage(cur ^ 1, (it + 1) * BK);  // async, drains at the barrier
#pragma unroll
    for (int kk = 0; kk < 2; ++kk) {
      short8 a[4], b[4];
#pragma unroll
      for (int m = 0; m < 4; ++m) {
        const int r = wr * 64 + m * 16 + lr;
        a[m] = *(const short8*)(&As[cur][r * BK + (((kk * 4 + lg) ^ (r & 7)) * 8)]);
      }
#pragma unroll
      for (int n = 0; n < 4; ++n) {
        const int r = wc * 64 + n * 16 + lr;
        b[n] = *(const short8*)(&Bs[cur][r * BK + (((kk * 4 + lg) ^ (r & 7)) * 8)]);
      }
#pragma unroll
      for (int m = 0; m < 4; ++m)
#pragma unroll
        for (int n = 0; n < 4; ++n)
          acc[m][n] = __builtin_amdgcn_mfma_f32_16x16x32_bf16(a[m], b[n], acc[m][n], 0, 0, 0);
    }
    __syncthreads();
  }
#pragma unroll
  for (int n = 0; n < 4; ++n) {
    const int col = n0 + wc * 64 + n * 16 + lr;
    const float bv = BIAS ? bias[col] : 0.0f;
#pragma unroll
    for (int m = 0; m < 4; ++m) {
#pragma unroll
      for (int r = 0; r < 4; ++r) {
        const int row = m0 + wr * 64 + m * 16 + lg * 4 + r;
        float v = acc[m][n][r] + bv;
        if (RELU) v = fmaxf(v, 0.0f);
        if (BF16OUT) Cb[(size_t)row * N + col] = f2b(v);
        else         Cf[(size_t)row * N + col] = v;
      }
    }
  }
}

// ---------------- transpose V: qkvb[:,1024:2048] ([N][D]) -> vt [D][N] ----------------
__global__ void transpose_v(const short* __restrict__ src, short* __restrict__ dst) {
  __shared__ short tile[64][65];
  const int bx = blockIdx.x * 64;  // d
  const int by = blockIdx.y * 64;  // n
  const int t = threadIdx.x;
  const int tx = t & 63, ty = t >> 6;
#pragma unroll
  for (int i = 0; i < 64; i += 4)
    tile[ty + i][tx] = src[(size_t)(by + ty + i) * 2048 + 1024 + bx + tx];
  __syncthreads();
#pragma unroll
  for (int i = 0; i < 64; i += 4)
    dst[(size_t)(bx + ty + i) * 2048 + by + tx] = tile[tx][ty + i];
}

// ---------------- flash attention, LDS-staged K/V, 4 waves/block (R6, unchanged) ----------------
__launch_bounds__(256, 2)
__global__ void flash_attn(const short* __restrict__ qk, const short* __restrict__ vt,
                           float* __restrict__ O) {
  const int t = threadIdx.x;
  const int l = t & 63, w = t >> 6;
  const int lr = l & 15, lg = l >> 4;
  const int h = blockIdx.y;
  const int qb = blockIdx.x;
  __shared__ short Ks[2][64 * 64];
  __shared__ short Vs[2][64 * 64];
  __shared__ short Pl[4][16][72];
  const float C2 = 0.18033688011112042f;  // (1/sqrt(64)) * log2(e)

  const int qrow = qb * 64 + w * 16 + lr;
  short8 aq[2];
#pragma unroll
  for (int f = 0; f < 2; ++f)
    aq[f] = *(const short8*)(qk + (size_t)qrow * 2048 + h * 64 + f * 32 + lg * 8);

  f32x4 o[4] = {};
  float mrun = -1e30f, lrun = 0.0f;

  auto stage = [&](int b, int kt) {
#pragma unroll
    for (int i = 0; i < 2; ++i) {
      const int chunk = i * 256 + w * 64 + l;
      const int r = chunk >> 3, c = chunk & 7;
      const int cs = c ^ (r & 7);
      gload_lds16(qk + (size_t)(kt * 64 + r) * 2048 + h * 64 + cs * 8,
                  &Ks[b][(size_t)(i * 256 + w * 64) * 8]);
    }
#pragma unroll
    for (int i = 0; i < 2; ++i) {
      const int chunk = i * 256 + w * 64 + l;
      const int r = chunk >> 3, c = chunk & 7;
      const int cs = c ^ (r & 7);
      gload_lds16(vt + (size_t)(h * 64 + r) * 2048 + kt * 64 + cs * 8,
                  &Vs[b][(size_t)(i * 256 + w * 64) * 8]);
    }
  };

  stage(0, 0);
  __syncthreads();

#pragma unroll 1
  for (int kt = 0; kt < 32; ++kt) {
    const int cur = kt & 1;
    if (kt + 1 < 32) stage(cur ^ 1, kt + 1);

    f32x4 s[4] = {};
#pragma unroll
    for (int f = 0; f < 2; ++f) {
      short8 kf[4];
#pragma unroll
      for (int n = 0; n < 4; ++n) {
        const int r = n * 16 + lr;
        kf[n] = *(const short8*)(&Ks[cur][r * 64 + (((f * 4 + lg) ^ (lr & 7)) * 8)]);
      }
#pragma unroll
      for (int n = 0; n < 4; ++n)
        s[n] = __builtin_amdgcn_mfma_f32_16x16x32_bf16(kf[n], aq[f], s[n], 0, 0, 0);
    }
    float m0 = fmaxf(fmaxf(s[0][0], s[0][1]), fmaxf(s[0][2], s[0][3]));
    float m1 = fmaxf(fmaxf(s[1][0], s[1][1]), fmaxf(s[1][2], s[1][3]));
    float m2 = fmaxf(fmaxf(s[2][0], s[2][1]), fmaxf(s[2][2], s[2][3]));
    float m3 = fmaxf(fmaxf(s[3][0], s[3][1]), fmaxf(s[3][2], s[3][3]));
    float tm = fmaxf(fmaxf(m0, m1), fmaxf(m2, m3));
    tm = fmaxf(tm, __shfl_xor(tm, 16));
    tm = fmaxf(tm, __shfl_xor(tm, 32));
    const float mnew = fmaxf(mrun, tm);
    const float corr = fexp2((mrun - mnew) * C2);
    mrun = mnew;
    float p[4][4];
#pragma unroll
    for (int n = 0; n < 4; ++n)
#pragma unroll
      for (int r = 0; r < 4; ++r)
        p[n][r] = fexp2((s[n][r] - mnew) * C2);
    float q0 = (p[0][0] + p[0][1]) + (p[0][2] + p[0][3]);
    float q1 = (p[1][0] + p[1][1]) + (p[1][2] + p[1][3]);
    float q2 = (p[2][0] + p[2][1]) + (p[2][2] + p[2][3]);
    float q3 = (p[3][0] + p[3][1]) + (p[3][2] + p[3][3]);
    float ps = (q0 + q1) + (q2 + q3);
    ps += __shfl_xor(ps, 16);
    ps += __shfl_xor(ps, 32);
    lrun = lrun * corr + ps;
    f32x4 cov;
#pragma unroll
    for (int r = 0; r < 4; ++r)
      cov[r] = __shfl(corr, lg * 4 + r);
#pragma unroll
    for (int n = 0; n < 4; ++n)
      o[n] *= cov;
#pragma unroll
    for (int n = 0; n < 4; ++n) {
      uint2 wv;
      wv.x = ((unsigned)(unsigned short)f2b(p[n][1]) << 16) | (unsigned short)f2b(p[n][0]);
      wv.y = ((unsigned)(unsigned short)f2b(p[n][3]) << 16) | (unsigned short)f2b(p[n][2]);
      *(uint2*)&Pl[w][lr][n * 16 + lg * 4] = wv;
    }
#pragma unroll
    for (int f = 0; f < 2; ++f) {
      short8 ap = *(const short8*)&Pl[w][lr][f * 32 + lg * 8];
      short8 vf[4];
#pragma unroll
      for (int n = 0; n < 4; ++n) {
        const int r = n * 16 + lr;
        vf[n] = *(const short8*)(&Vs[cur][r * 64 + (((f * 4 + lg) ^ (lr & 7)) * 8)]);
      }
#pragma unroll
      for (int n = 0; n < 4; ++n)
        o[n] = __builtin_amdgcn_mfma_f32_16x16x32_bf16(ap, vf[n], o[n], 0, 0, 0);
    }
    __syncthreads();
  }

  f32x4 inv;
#pragma unroll
  for (int r = 0; r < 4; ++r)
    inv[r] = 1.0f / __shfl(lrun, lg * 4 + r);
#pragma unroll
  for (int n = 0; n < 4; ++n)
#pragma unroll
    for (int r = 0; r < 4; ++r)
      O[(size_t)(qb * 64 + w * 16 + lg * 4 + r) * 1024 + h * 64 + n * 16 + lr] = o[n][r] * inv[r];
}

// ---------------- out = LN(A + B0 [+ B1] [+ bias]) * g + be ----------------
__launch_bounds__(256)
__global__ void add_ln(const float* __restrict__ A, const float* __restrict__ B0,
                       const float* __restrict__ B1, const float* __restrict__ bias,
                       const float* __restrict__ g, const float* __restrict__ be,
                       float* __restrict__ outf, short* __restrict__ outb) {
  const int row = blockIdx.x;
  const int t = threadIdx.x;
  const size_t base = (size_t)row * 1024 + t * 4;
  float4 a = *(const float4*)(A + base);
  float4 b = *(const float4*)(B0 + base);
  float4 s; s.x = a.x + b.x; s.y = a.y + b.y; s.z = a.z + b.z; s.w = a.w + b.w;
  if (B1) {
    float4 c = *(const float4*)(B1 + base);
    s.x += c.x; s.y += c.y; s.z += c.z; s.w += c.w;
  }
  if (bias) {
    float4 c = *(const float4*)(bias + t * 4);
    s.x += c.x; s.y += c.y; s.z += c.z; s.w += c.w;
  }
  float sum = s.x + s.y + s.z + s.w;
  float sq  = s.x * s.x + s.y * s.y + s.z * s.z + s.w * s.w;
#pragma unroll
  for (int d = 32; d > 0; d >>= 1) {
    sum += __shfl_down(sum, d);
    sq  += __shfl_down(sq, d);
  }
  __shared__ float red[8];
  const int w = t >> 6, l = t & 63;
  if (l == 0) { red[w] = sum; red[4 + w] = sq; }
  __syncthreads();
  sum = red[0] + red[1] + red[2] + red[3];
  sq  = red[4] + red[5] + red[6] + red[7];
  const float mu = sum * (1.0f / 1024.0f);
  const float rstd = rsqrtf(sq * (1.0f / 1024.0f) - mu * mu + 1e-5f);
  float4 gv = *(const float4*)(g + t * 4);
  float4 bv = *(const float4*)(be + t * 4);
  float4 o;
  o.x = (s.x - mu) * rstd * gv.x + bv.x;
  o.y = (s.y - mu) * rstd * gv.y + bv.y;
  o.z = (s.z - mu) * rstd * gv.z + bv.z;
  o.w = (s.w - mu) * rstd * gv.w + bv.w;
  *(float4*)(outf + base) = o;
  if (outb) {
    short4v ob; ob.x = f2b(o.x); ob.y = f2b(o.y); ob.z = f2b(o.z); ob.w = f2b(o.w);
    *(short4v*)(outb + base) = ob;
  }
}

extern "C" void kernel_launch(void* const* d_in, const int* in_sizes, int n_in,
                              void* d_out, int out_size, void* d_ws, size_t ws_size,
                              hipStream_t stream) {
  const float* X    = (const float*)d_in[0];
  const float* Wqkv = (const float*)d_in[1];
  const float* W1   = (const float*)d_in[2];
  const float* b1   = (const float*)d_in[3];
  const float* W2   = (const float*)d_in[4];
  const float* b2   = (const float*)d_in[5];
  const float* g1   = (const float*)d_in[6];
  const float* be1  = (const float*)d_in[7];
  const float* g2   = (const float*)d_in[8];
  const float* be2  = (const float*)d_in[9];

  // workspace, explicit offsets (60 MiB peak). Live steps:
  // 1 cast -> 2 QKV -> 3 transpose -> 4 flash -> 5 LN1 -> 6 FFN1 -> 7 FFN2 -> 8 LN2
  //  W1b   [0,8)   live 1-6
  //  W2b   [8,16)  live 1-7
  //  h     [16,24) live 5-8
  //  hb    [24,28) live 5-6
  //  qkvb  [28,36) live 2-4   | y1b [28,44) live 6-7
  //  vt    [36,40) live 3-4
  //  attn  [44,52) live 4-5   | P0/P1 [44,60) live 7-8
  //  Xb    [52,56) live 1-2
  //  Wqkvb [56,60) live 1-2
  char* ws = (char*)d_ws;
  const size_t MiB = 1u << 20;
  short*  W1b   = (short*)(ws + 0 * MiB);
  short*  W2b   = (short*)(ws + 8 * MiB);
  float*  h     = (float*)(ws + 16 * MiB);
  short*  hb    = (short*)(ws + 24 * MiB);
  short*  qkvb  = (short*)(ws + 28 * MiB);
  short*  y1b   = (short*)(ws + 28 * MiB);
  short*  vt    = (short*)(ws + 36 * MiB);
  float*  attn  = (float*)(ws + 44 * MiB);
  float*  P0    = (float*)(ws + 44 * MiB);
  float*  P1    = P0 + (size_t)NTOK * DMODEL;
  short*  Xb    = (short*)(ws + 52 * MiB);
  short*  Wqkvb = (short*)(ws + 56 * MiB);

  cast_all<<<6144, 256, 0, stream>>>(X, Xb, NTOK * DMODEL / 8,
                                     Wqkv, Wqkvb, 2 * DMODEL * DMODEL / 8,
                                     W1, W1b, DFF * DMODEL / 8,
                                     W2, W2b, DMODEL * DFF / 8);

  {  // qkv = X @ Wqkv^T -> bf16 [2048, 2048]
    dim3 grid(2 * DMODEL / 128, NTOK / 128, 1);
    gemm_bt<128, 128, 2, 2, true, false, false><<<grid, 256, 0, stream>>>(
        Xb, Wqkvb, nullptr, nullptr, qkvb, NTOK, 2 * DMODEL, DMODEL, DMODEL, DMODEL, 0);
  }
  {  // vt[d][n] = v[n][d]
    dim3 grid(DMODEL / 64, NTOK / 64);
    transpose_v<<<grid, 256, 0, stream>>>(qkvb, vt);
  }
  {  // attn_out f32 [2048, 1024]
    dim3 grid(NTOK / 64, NHEAD);
    flash_attn<<<grid, 256, 0, stream>>>(qkvb, vt, attn);
  }
  add_ln<<<NTOK, 256, 0, stream>>>(X, attn, nullptr, nullptr, g1, be1, h, hb);
  {  // y1 = relu(h @ W1^T + b1) -> bf16 [2048, 4096]
    dim3 grid(DFF / 128, NTOK / 128, 1);
    gemm_bt<128, 128, 2, 2, true, true, true><<<grid, 256, 0, stream>>>(
        hb, W1b, b1, nullptr, y1b, NTOK, DFF, DMODEL, DMODEL, DMODEL, 0);
  }
  {  // ffn2 partials: split-K=2; bias b2 folded into LN2
    dim3 grid(DMODEL / 128, NTOK / 128, 2);
    gemm_bt<128, 128, 2, 2, false, false, false><<<grid, 256, 0, stream>>>(
        y1b, W2b, nullptr, P0, nullptr, NTOK, DMODEL, 2048, DFF, DFF, 2048);
  }
  add_ln<<<NTOK, 256, 0, stream>>>(h, P0, P1, b2, g2, be2, (float*)d_out, nullptr);
}

// Round 8
// 243.858 us; speedup vs baseline: 1.4641x; 1.0298x over previous
//
#include <hip/hip_runtime.h>
#include <stdint.h>

// TransformerBlock on MI355X (gfx950), bf16-MFMA. Round 8.
// vs R7: (1) GEMMs move to BM=64/BN=128 tiles (48KB LDS -> 3 blocks/CU, 2x grid)
// with generic MR/NR fragment counts — attacks latency-bound regime via more
// independent barrier groups per CU. (2) flash: exact-skip defer-max (corr==1
// path skipped under wave-uniform __any, zero numerical change) + s_setprio(1)
// around MFMA clusters. Everything else unchanged.

#define NTOK 2048
#define DMODEL 1024
#define NHEAD 16
#define DHEAD 64
#define DFF 4096

typedef __attribute__((ext_vector_type(8))) short short8;
typedef __attribute__((ext_vector_type(4))) short short4v;
typedef __attribute__((ext_vector_type(4))) float f32x4;

__device__ __forceinline__ float fexp2(float x) { return __builtin_amdgcn_exp2f(x); }

// fp32 -> bf16 RNE
__device__ __forceinline__ short f2b(float f) {
  union { float f; unsigned u; } v; v.f = f;
  unsigned r = v.u + 0x7fffu + ((v.u >> 16) & 1u);
  return (short)(r >> 16);
}

__device__ __forceinline__ void gload_lds16(const void* g, void* l) {
  __builtin_amdgcn_global_load_lds((const __attribute__((address_space(1))) void*)g,
                                   (__attribute__((address_space(3))) void*)l,
                                   16, 0, 0);
}

// ---------------- fused cast fp32 -> bf16 for 4 tensors ----------------
__global__ void cast_all(const float* __restrict__ s0, short* __restrict__ d0, int n0,
                         const float* __restrict__ s1, short* __restrict__ d1, int n1,
                         const float* __restrict__ s2, short* __restrict__ d2, int n2,
                         const float* __restrict__ s3, short* __restrict__ d3, int n3) {
  int i = blockIdx.x * blockDim.x + threadIdx.x;
  const float* s; short* d; int j = i;
  if (j < n0) { s = s0; d = d0; }
  else { j -= n0;
    if (j < n1) { s = s1; d = d1; }
    else { j -= n1;
      if (j < n2) { s = s2; d = d2; }
      else { j -= n2; if (j >= n3) return; s = s3; d = d3; }
    }
  }
  const float4* p = (const float4*)(s + (size_t)j * 8);
  float4 a = p[0], b = p[1];
  short8 o;
  o[0] = f2b(a.x); o[1] = f2b(a.y); o[2] = f2b(a.z); o[3] = f2b(a.w);
  o[4] = f2b(b.x); o[5] = f2b(b.y); o[6] = f2b(b.z); o[7] = f2b(b.w);
  *(short8*)(d + (size_t)j * 8) = o;
}

// ---------------- GEMM: C = A @ B^T (+relu/bias), bf16 in, f32 acc ----------------
// BK=64, LDS double-buffered, 1 barrier/iter (stage-next -> compute-cur -> sync).
// LDS layout: [row][8 chunks of 16B], slot (r,c) holds global chunk (r, c^(r&7)).
// Wave (wr,wc) owns a (BM/WR)x(BN/WC) sub-tile -> MR x NR fragments of 16x16.
template<int BM, int BN, int WR, int WC, bool BF16OUT, bool BIAS, bool RELU>
__launch_bounds__(WR * WC * 64, 3)
__global__ void gemm_bt(const short* __restrict__ A, const short* __restrict__ B,
                        const float* __restrict__ bias,
                        float* __restrict__ Cf, short* __restrict__ Cb,
                        int M, int N, int K, int lda, int ldb, int kstep) {
  constexpr int BK = 64;
  constexpr int THREADS = WR * WC * 64;
  constexpr int ACH = (BM * (BK / 8)) / THREADS;
  constexpr int BCH = (BN * (BK / 8)) / THREADS;
  constexpr int MR = BM / (WR * 16);
  constexpr int NR = BN / (WC * 16);
  __shared__ short As[2][BM * BK];
  __shared__ short Bs[2][BN * BK];
  const int t = threadIdx.x;
  const int l = t & 63;
  const int w = t >> 6;
  const int wr = w / WC, wc = w % WC;
  const int lr = l & 15, lg = l >> 4;
  const int m0 = blockIdx.y * BM, n0 = blockIdx.x * BN;
  const int koff = blockIdx.z * kstep;
  A += koff; B += koff;
  Cf += (size_t)blockIdx.z * M * N;

  auto stage = [&](int b, int k0) {
#pragma unroll
    for (int i = 0; i < ACH; ++i) {
      const int ci = i * THREADS + t;
      const int r = ci >> 3, c = ci & 7;
      const int cs = c ^ (r & 7);
      gload_lds16(A + (size_t)(m0 + r) * lda + k0 + cs * 8,
                  &As[b][(size_t)(i * THREADS + w * 64) * 8]);
    }
#pragma unroll
    for (int i = 0; i < BCH; ++i) {
      const int ci = i * THREADS + t;
      const int r = ci >> 3, c = ci & 7;
      const int cs = c ^ (r & 7);
      gload_lds16(B + (size_t)(n0 + r) * ldb + k0 + cs * 8,
                  &Bs[b][(size_t)(i * THREADS + w * 64) * 8]);
    }
  };

  f32x4 acc[MR][NR] = {};
  const int nIter = K / BK;
  stage(0, 0);
  __syncthreads();
  for (int it = 0; it < nIter; ++it) {
    const int cur = it & 1;
    if (it + 1 < nIter) stage(cur ^ 1, (it + 1) * BK);  // async, drains at the barrier
#pragma unroll
    for (int kk = 0; kk < 2; ++kk) {
      short8 a[MR], b[NR];
#pragma unroll
      for (int m = 0; m < MR; ++m) {
        const int r = wr * (BM / WR) + m * 16 + lr;
        a[m] = *(const short8*)(&As[cur][r * BK + (((kk * 4 + lg) ^ (r & 7)) * 8)]);
      }
#pragma unroll
      for (int n = 0; n < NR; ++n) {
        const int r = wc * (BN / WC) + n * 16 + lr;
        b[n] = *(const short8*)(&Bs[cur][r * BK + (((kk * 4 + lg) ^ (r & 7)) * 8)]);
      }
#pragma unroll
      for (int m = 0; m < MR; ++m)
#pragma unroll
        for (int n = 0; n < NR; ++n)
          acc[m][n] = __builtin_amdgcn_mfma_f32_16x16x32_bf16(a[m], b[n], acc[m][n], 0, 0, 0);
    }
    __syncthreads();
  }
#pragma unroll
  for (int n = 0; n < NR; ++n) {
    const int col = n0 + wc * (BN / WC) + n * 16 + lr;
    const float bv = BIAS ? bias[col] : 0.0f;
#pragma unroll
    for (int m = 0; m < MR; ++m) {
#pragma unroll
      for (int r = 0; r < 4; ++r) {
        const int row = m0 + wr * (BM / WR) + m * 16 + lg * 4 + r;
        float v = acc[m][n][r] + bv;
        if (RELU) v = fmaxf(v, 0.0f);
        if (BF16OUT) Cb[(size_t)row * N + col] = f2b(v);
        else         Cf[(size_t)row * N + col] = v;
      }
    }
  }
}

// ---------------- transpose V: qkvb[:,1024:2048] ([N][D]) -> vt [D][N] ----------------
__global__ void transpose_v(const short* __restrict__ src, short* __restrict__ dst) {
  __shared__ short tile[64][65];
  const int bx = blockIdx.x * 64;  // d
  const int by = blockIdx.y * 64;  // n
  const int t = threadIdx.x;
  const int tx = t & 63, ty = t >> 6;
#pragma unroll
  for (int i = 0; i < 64; i += 4)
    tile[ty + i][tx] = src[(size_t)(by + ty + i) * 2048 + 1024 + bx + tx];
  __syncthreads();
#pragma unroll
  for (int i = 0; i < 64; i += 4)
    dst[(size_t)(bx + ty + i) * 2048 + by + tx] = tile[tx][ty + i];
}

// ---------------- flash attention, LDS-staged K/V, 4 waves/block ----------------
// R6 structure + exact-skip defer-max + setprio around MFMA clusters.
__launch_bounds__(256, 2)
__global__ void flash_attn(const short* __restrict__ qk, const short* __restrict__ vt,
                           float* __restrict__ O) {
  const int t = threadIdx.x;
  const int l = t & 63, w = t >> 6;
  const int lr = l & 15, lg = l >> 4;
  const int h = blockIdx.y;
  const int qb = blockIdx.x;
  __shared__ short Ks[2][64 * 64];
  __shared__ short Vs[2][64 * 64];
  __shared__ short Pl[4][16][72];
  const float C2 = 0.18033688011112042f;  // (1/sqrt(64)) * log2(e)

  const int qrow = qb * 64 + w * 16 + lr;
  short8 aq[2];
#pragma unroll
  for (int f = 0; f < 2; ++f)
    aq[f] = *(const short8*)(qk + (size_t)qrow * 2048 + h * 64 + f * 32 + lg * 8);

  f32x4 o[4] = {};
  float mrun = -1e30f, lrun = 0.0f;

  auto stage = [&](int b, int kt) {
#pragma unroll
    for (int i = 0; i < 2; ++i) {
      const int chunk = i * 256 + w * 64 + l;
      const int r = chunk >> 3, c = chunk & 7;
      const int cs = c ^ (r & 7);
      gload_lds16(qk + (size_t)(kt * 64 + r) * 2048 + h * 64 + cs * 8,
                  &Ks[b][(size_t)(i * 256 + w * 64) * 8]);
    }
#pragma unroll
    for (int i = 0; i < 2; ++i) {
      const int chunk = i * 256 + w * 64 + l;
      const int r = chunk >> 3, c = chunk & 7;
      const int cs = c ^ (r & 7);
      gload_lds16(vt + (size_t)(h * 64 + r) * 2048 + kt * 64 + cs * 8,
                  &Vs[b][(size_t)(i * 256 + w * 64) * 8]);
    }
  };

  stage(0, 0);
  __syncthreads();

#pragma unroll 1
  for (int kt = 0; kt < 32; ++kt) {
    const int cur = kt & 1;
    if (kt + 1 < 32) stage(cur ^ 1, kt + 1);

    f32x4 s[4] = {};
    __builtin_amdgcn_s_setprio(1);
#pragma unroll
    for (int f = 0; f < 2; ++f) {
      short8 kf[4];
#pragma unroll
      for (int n = 0; n < 4; ++n) {
        const int r = n * 16 + lr;
        kf[n] = *(const short8*)(&Ks[cur][r * 64 + (((f * 4 + lg) ^ (lr & 7)) * 8)]);
      }
#pragma unroll
      for (int n = 0; n < 4; ++n)
        s[n] = __builtin_amdgcn_mfma_f32_16x16x32_bf16(kf[n], aq[f], s[n], 0, 0, 0);
    }
    __builtin_amdgcn_s_setprio(0);
    float m0 = fmaxf(fmaxf(s[0][0], s[0][1]), fmaxf(s[0][2], s[0][3]));
    float m1 = fmaxf(fmaxf(s[1][0], s[1][1]), fmaxf(s[1][2], s[1][3]));
    float m2 = fmaxf(fmaxf(s[2][0], s[2][1]), fmaxf(s[2][2], s[2][3]));
    float m3 = fmaxf(fmaxf(s[3][0], s[3][1]), fmaxf(s[3][2], s[3][3]));
    float tm = fmaxf(fmaxf(m0, m1), fmaxf(m2, m3));
    tm = fmaxf(tm, __shfl_xor(tm, 16));
    tm = fmaxf(tm, __shfl_xor(tm, 32));
    // exact-skip defer-max: if no row's max grew, corr==1 -> skip rescale
    float corrv = 1.0f;
    if (__any(tm > mrun)) {
      const float mnew = fmaxf(mrun, tm);
      corrv = fexp2((mrun - mnew) * C2);
      mrun = mnew;
      f32x4 cov;
#pragma unroll
      for (int r = 0; r < 4; ++r)
        cov[r] = __shfl(corrv, lg * 4 + r);
#pragma unroll
      for (int n = 0; n < 4; ++n)
        o[n] *= cov;
    }
    float p[4][4];
#pragma unroll
    for (int n = 0; n < 4; ++n)
#pragma unroll
      for (int r = 0; r < 4; ++r)
        p[n][r] = fexp2((s[n][r] - mrun) * C2);
    float q0 = (p[0][0] + p[0][1]) + (p[0][2] + p[0][3]);
    float q1 = (p[1][0] + p[1][1]) + (p[1][2] + p[1][3]);
    float q2 = (p[2][0] + p[2][1]) + (p[2][2] + p[2][3]);
    float q3 = (p[3][0] + p[3][1]) + (p[3][2] + p[3][3]);
    float ps = (q0 + q1) + (q2 + q3);
    ps += __shfl_xor(ps, 16);
    ps += __shfl_xor(ps, 32);
    lrun = lrun * corrv + ps;
#pragma unroll
    for (int n = 0; n < 4; ++n) {
      uint2 wv;
      wv.x = ((unsigned)(unsigned short)f2b(p[n][1]) << 16) | (unsigned short)f2b(p[n][0]);
      wv.y = ((unsigned)(unsigned short)f2b(p[n][3]) << 16) | (unsigned short)f2b(p[n][2]);
      *(uint2*)&Pl[w][lr][n * 16 + lg * 4] = wv;
    }
    __builtin_amdgcn_s_setprio(1);
#pragma unroll
    for (int f = 0; f < 2; ++f) {
      short8 ap = *(const short8*)&Pl[w][lr][f * 32 + lg * 8];
      short8 vf[4];
#pragma unroll
      for (int n = 0; n < 4; ++n) {
        const int r = n * 16 + lr;
        vf[n] = *(const short8*)(&Vs[cur][r * 64 + (((f * 4 + lg) ^ (lr & 7)) * 8)]);
      }
#pragma unroll
      for (int n = 0; n < 4; ++n)
        o[n] = __builtin_amdgcn_mfma_f32_16x16x32_bf16(ap, vf[n], o[n], 0, 0, 0);
    }
    __builtin_amdgcn_s_setprio(0);
    __syncthreads();
  }

  f32x4 inv;
#pragma unroll
  for (int r = 0; r < 4; ++r)
    inv[r] = 1.0f / __shfl(lrun, lg * 4 + r);
#pragma unroll
  for (int n = 0; n < 4; ++n)
#pragma unroll
    for (int r = 0; r < 4; ++r)
      O[(size_t)(qb * 64 + w * 16 + lg * 4 + r) * 1024 + h * 64 + n * 16 + lr] = o[n][r] * inv[r];
}

// ---------------- out = LN(A + B0 [+ B1] [+ bias]) * g + be ----------------
__launch_bounds__(256)
__global__ void add_ln(const float* __restrict__ A, const float* __restrict__ B0,
                       const float* __restrict__ B1, const float* __restrict__ bias,
                       const float* __restrict__ g, const float* __restrict__ be,
                       float* __restrict__ outf, short* __restrict__ outb) {
  const int row = blockIdx.x;
  const int t = threadIdx.x;
  const size_t base = (size_t)row * 1024 + t * 4;
  float4 a = *(const float4*)(A + base);
  float4 b = *(const float4*)(B0 + base);
  float4 s; s.x = a.x + b.x; s.y = a.y + b.y; s.z = a.z + b.z; s.w = a.w + b.w;
  if (B1) {
    float4 c = *(const float4*)(B1 + base);
    s.x += c.x; s.y += c.y; s.z += c.z; s.w += c.w;
  }
  if (bias) {
    float4 c = *(const float4*)(bias + t * 4);
    s.x += c.x; s.y += c.y; s.z += c.z; s.w += c.w;
  }
  float sum = s.x + s.y + s.z + s.w;
  float sq  = s.x * s.x + s.y * s.y + s.z * s.z + s.w * s.w;
#pragma unroll
  for (int d = 32; d > 0; d >>= 1) {
    sum += __shfl_down(sum, d);
    sq  += __shfl_down(sq, d);
  }
  __shared__ float red[8];
  const int w = t >> 6, l = t & 63;
  if (l == 0) { red[w] = sum; red[4 + w] = sq; }
  __syncthreads();
  sum = red[0] + red[1] + red[2] + red[3];
  sq  = red[4] + red[5] + red[6] + red[7];
  const float mu = sum * (1.0f / 1024.0f);
  const float rstd = rsqrtf(sq * (1.0f / 1024.0f) - mu * mu + 1e-5f);
  float4 gv = *(const float4*)(g + t * 4);
  float4 bv = *(const float4*)(be + t * 4);
  float4 o;
  o.x = (s.x - mu) * rstd * gv.x + bv.x;
  o.y = (s.y - mu) * rstd * gv.y + bv.y;
  o.z = (s.z - mu) * rstd * gv.z + bv.z;
  o.w = (s.w - mu) * rstd * gv.w + bv.w;
  *(float4*)(outf + base) = o;
  if (outb) {
    short4v ob; ob.x = f2b(o.x); ob.y = f2b(o.y); ob.z = f2b(o.z); ob.w = f2b(o.w);
    *(short4v*)(outb + base) = ob;
  }
}

extern "C" void kernel_launch(void* const* d_in, const int* in_sizes, int n_in,
                              void* d_out, int out_size, void* d_ws, size_t ws_size,
                              hipStream_t stream) {
  const float* X    = (const float*)d_in[0];
  const float* Wqkv = (const float*)d_in[1];
  const float* W1   = (const float*)d_in[2];
  const float* b1   = (const float*)d_in[3];
  const float* W2   = (const float*)d_in[4];
  const float* b2   = (const float*)d_in[5];
  const float* g1   = (const float*)d_in[6];
  const float* be1  = (const float*)d_in[7];
  const float* g2   = (const float*)d_in[8];
  const float* be2  = (const float*)d_in[9];

  // workspace, explicit offsets (60 MiB peak) — unchanged from R7.
  char* ws = (char*)d_ws;
  const size_t MiB = 1u << 20;
  short*  W1b   = (short*)(ws + 0 * MiB);
  short*  W2b   = (short*)(ws + 8 * MiB);
  float*  h     = (float*)(ws + 16 * MiB);
  short*  hb    = (short*)(ws + 24 * MiB);
  short*  qkvb  = (short*)(ws + 28 * MiB);
  short*  y1b   = (short*)(ws + 28 * MiB);
  short*  vt    = (short*)(ws + 36 * MiB);
  float*  attn  = (float*)(ws + 44 * MiB);
  float*  P0    = (float*)(ws + 44 * MiB);
  float*  P1    = P0 + (size_t)NTOK * DMODEL;
  short*  Xb    = (short*)(ws + 52 * MiB);
  short*  Wqkvb = (short*)(ws + 56 * MiB);

  cast_all<<<6144, 256, 0, stream>>>(X, Xb, NTOK * DMODEL / 8,
                                     Wqkv, Wqkvb, 2 * DMODEL * DMODEL / 8,
                                     W1, W1b, DFF * DMODEL / 8,
                                     W2, W2b, DMODEL * DFF / 8);

  {  // qkv = X @ Wqkv^T -> bf16 [2048, 2048]; 512 blocks, 3/CU
    dim3 grid(2 * DMODEL / 128, NTOK / 64, 1);
    gemm_bt<64, 128, 2, 2, true, false, false><<<grid, 256, 0, stream>>>(
        Xb, Wqkvb, nullptr, nullptr, qkvb, NTOK, 2 * DMODEL, DMODEL, DMODEL, DMODEL, 0);
  }
  {  // vt[d][n] = v[n][d]
    dim3 grid(DMODEL / 64, NTOK / 64);
    transpose_v<<<grid, 256, 0, stream>>>(qkvb, vt);
  }
  {  // attn_out f32 [2048, 1024]
    dim3 grid(NTOK / 64, NHEAD);
    flash_attn<<<grid, 256, 0, stream>>>(qkvb, vt, attn);
  }
  add_ln<<<NTOK, 256, 0, stream>>>(X, attn, nullptr, nullptr, g1, be1, h, hb);
  {  // y1 = relu(h @ W1^T + b1) -> bf16 [2048, 4096]; 1024 blocks
    dim3 grid(DFF / 128, NTOK / 64, 1);
    gemm_bt<64, 128, 2, 2, true, true, true><<<grid, 256, 0, stream>>>(
        hb, W1b, b1, nullptr, y1b, NTOK, DFF, DMODEL, DMODEL, DMODEL, 0);
  }
  {  // ffn2 partials: split-K=2; 512 blocks; bias b2 folded into LN2
    dim3 grid(DMODEL / 128, NTOK / 64, 2);
    gemm_bt<64, 128, 2, 2, false, false, false><<<grid, 256, 0, stream>>>(
        y1b, W2b, nullptr, P0, nullptr, NTOK, DMODEL, 2048, DFF, DFF, 2048);
  }
  add_ln<<<NTOK, 256, 0, stream>>>(h, P0, P1, b2, g2, be2, (float*)d_out, nullptr);
}

// Round 9
// 235.251 us; speedup vs baseline: 1.5176x; 1.0366x over previous
//
#include <hip/hip_runtime.h>
#include <stdint.h>

// TransformerBlock on MI355X (gfx950), bf16-MFMA. Round 9.
// vs R8: gemm_bt gets (1) 3-buffer 2-deep prefetch with counted s_waitcnt
// vmcnt(6) + raw s_barrier (loads stay in flight across barriers — T4), and
// (2) bijective XCD-aware tile swizzle (column-chunked -> weight panels
// L2-resident — T1). Flash/LN/cast/transpose unchanged from R8.

#define NTOK 2048
#define DMODEL 1024
#define NHEAD 16
#define DHEAD 64
#define DFF 4096

typedef __attribute__((ext_vector_type(8))) short short8;
typedef __attribute__((ext_vector_type(4))) short short4v;
typedef __attribute__((ext_vector_type(4))) float f32x4;

__device__ __forceinline__ float fexp2(float x) { return __builtin_amdgcn_exp2f(x); }

// fp32 -> bf16 RNE
__device__ __forceinline__ short f2b(float f) {
  union { float f; unsigned u; } v; v.f = f;
  unsigned r = v.u + 0x7fffu + ((v.u >> 16) & 1u);
  return (short)(r >> 16);
}

__device__ __forceinline__ void gload_lds16(const void* g, void* l) {
  __builtin_amdgcn_global_load_lds((const __attribute__((address_space(1))) void*)g,
                                   (__attribute__((address_space(3))) void*)l,
                                   16, 0, 0);
}

// ---------------- fused cast fp32 -> bf16 for 4 tensors ----------------
__global__ void cast_all(const float* __restrict__ s0, short* __restrict__ d0, int n0,
                         const float* __restrict__ s1, short* __restrict__ d1, int n1,
                         const float* __restrict__ s2, short* __restrict__ d2, int n2,
                         const float* __restrict__ s3, short* __restrict__ d3, int n3) {
  int i = blockIdx.x * blockDim.x + threadIdx.x;
  const float* s; short* d; int j = i;
  if (j < n0) { s = s0; d = d0; }
  else { j -= n0;
    if (j < n1) { s = s1; d = d1; }
    else { j -= n1;
      if (j < n2) { s = s2; d = d2; }
      else { j -= n2; if (j >= n3) return; s = s3; d = d3; }
    }
  }
  const float4* p = (const float4*)(s + (size_t)j * 8);
  float4 a = p[0], b = p[1];
  short8 o;
  o[0] = f2b(a.x); o[1] = f2b(a.y); o[2] = f2b(a.z); o[3] = f2b(a.w);
  o[4] = f2b(b.x); o[5] = f2b(b.y); o[6] = f2b(b.z); o[7] = f2b(b.w);
  *(short8*)(d + (size_t)j * 8) = o;
}

// ---------------- GEMM: C = A @ B^T (+relu/bias), bf16 in, f32 acc ----------------
// BK=64; 3 LDS buffers; 2-deep prefetch; one raw s_barrier per iter with
// counted vmcnt (per-wave: 6 loads/stage; steady outstanding 12 -> wait 6).
// Safety: lockstep bodies (1 barrier/iter); buf written at body kt was last
// read in body kt-1; each wave waits its OWN kt-loads before the barrier.
// XCD swizzle: column-major flat id chunked across 8 XCDs (bijective; all
// grids have nwg_xy % 8 == 0).
template<int BM, int BN, int WR, int WC, bool BF16OUT, bool BIAS, bool RELU>
__launch_bounds__(WR * WC * 64, 2)
__global__ void gemm_bt(const short* __restrict__ A, const short* __restrict__ B,
                        const float* __restrict__ bias,
                        float* __restrict__ Cf, short* __restrict__ Cb,
                        int M, int N, int K, int lda, int ldb, int kstep) {
  constexpr int BK = 64;
  constexpr int THREADS = WR * WC * 64;
  constexpr int ACH = (BM * (BK / 8)) / THREADS;
  constexpr int BCH = (BN * (BK / 8)) / THREADS;
  constexpr int LPS = ACH + BCH;  // vmem loads per stage per thread
  constexpr int MR = BM / (WR * 16);
  constexpr int NR = BN / (WC * 16);
  __shared__ short As[3][BM * BK];
  __shared__ short Bs[3][BN * BK];
  const int t = threadIdx.x;
  const int l = t & 63;
  const int w = t >> 6;
  const int wr = w / WC, wc = w % WC;
  const int lr = l & 15, lg = l >> 4;

  // XCD-aware bijective remap, column-major chunking (bx-groups per XCD)
  const int gx = gridDim.x, gy = gridDim.y;
  const int nxy = gx * gy;                      // % 8 == 0 for all call sites
  const int flat = blockIdx.x * gy + blockIdx.y;
  const int nf = (flat & 7) * (nxy >> 3) + (flat >> 3);
  const int bx = nf / gy, by = nf % gy;

  const int m0 = by * BM, n0 = bx * BN;
  const int koff = blockIdx.z * kstep;
  A += koff; B += koff;
  Cf += (size_t)blockIdx.z * M * N;

  auto stage = [&](int b, int k0) {
#pragma unroll
    for (int i = 0; i < ACH; ++i) {
      const int ci = i * THREADS + t;
      const int r = ci >> 3, c = ci & 7;
      const int cs = c ^ (r & 7);
      gload_lds16(A + (size_t)(m0 + r) * lda + k0 + cs * 8,
                  &As[b][(size_t)(i * THREADS + w * 64) * 8]);
    }
#pragma unroll
    for (int i = 0; i < BCH; ++i) {
      const int ci = i * THREADS + t;
      const int r = ci >> 3, c = ci & 7;
      const int cs = c ^ (r & 7);
      gload_lds16(B + (size_t)(n0 + r) * ldb + k0 + cs * 8,
                  &Bs[b][(size_t)(i * THREADS + w * 64) * 8]);
    }
  };

  f32x4 acc[MR][NR] = {};
  const int nIter = K / BK;
  stage(0, 0);
  if (1 < nIter) stage(1, BK);
  for (int it = 0; it < nIter; ++it) {
    const int cur = it % 3;
    // wait for THIS tile's loads (oldest LPS of outstanding), keep next in flight
    if (it + 1 < nIter) {
      static_assert(LPS == 6, "vmcnt literal assumes 6 loads/stage");
      asm volatile("s_waitcnt vmcnt(6)" ::: "memory");
    } else {
      asm volatile("s_waitcnt vmcnt(0)" ::: "memory");
    }
    __builtin_amdgcn_sched_barrier(0);
    __builtin_amdgcn_s_barrier();
    __builtin_amdgcn_sched_barrier(0);
#pragma unroll
    for (int kk = 0; kk < 2; ++kk) {
      short8 a[MR], b[NR];
#pragma unroll
      for (int m = 0; m < MR; ++m) {
        const int r = wr * (BM / WR) + m * 16 + lr;
        a[m] = *(const short8*)(&As[cur][r * BK + (((kk * 4 + lg) ^ (r & 7)) * 8)]);
      }
#pragma unroll
      for (int n = 0; n < NR; ++n) {
        const int r = wc * (BN / WC) + n * 16 + lr;
        b[n] = *(const short8*)(&Bs[cur][r * BK + (((kk * 4 + lg) ^ (r & 7)) * 8)]);
      }
#pragma unroll
      for (int m = 0; m < MR; ++m)
#pragma unroll
        for (int n = 0; n < NR; ++n)
          acc[m][n] = __builtin_amdgcn_mfma_f32_16x16x32_bf16(a[m], b[n], acc[m][n], 0, 0, 0);
    }
    if (it + 2 < nIter) stage((it + 2) % 3, (it + 2) * BK);
  }
#pragma unroll
  for (int n = 0; n < NR; ++n) {
    const int col = n0 + wc * (BN / WC) + n * 16 + lr;
    const float bv = BIAS ? bias[col] : 0.0f;
#pragma unroll
    for (int m = 0; m < MR; ++m) {
#pragma unroll
      for (int r = 0; r < 4; ++r) {
        const int row = m0 + wr * (BM / WR) + m * 16 + lg * 4 + r;
        float v = acc[m][n][r] + bv;
        if (RELU) v = fmaxf(v, 0.0f);
        if (BF16OUT) Cb[(size_t)row * N + col] = f2b(v);
        else         Cf[(size_t)row * N + col] = v;
      }
    }
  }
}

// ---------------- transpose V: qkvb[:,1024:2048] ([N][D]) -> vt [D][N] ----------------
__global__ void transpose_v(const short* __restrict__ src, short* __restrict__ dst) {
  __shared__ short tile[64][65];
  const int bx = blockIdx.x * 64;  // d
  const int by = blockIdx.y * 64;  // n
  const int t = threadIdx.x;
  const int tx = t & 63, ty = t >> 6;
#pragma unroll
  for (int i = 0; i < 64; i += 4)
    tile[ty + i][tx] = src[(size_t)(by + ty + i) * 2048 + 1024 + bx + tx];
  __syncthreads();
#pragma unroll
  for (int i = 0; i < 64; i += 4)
    dst[(size_t)(bx + ty + i) * 2048 + by + tx] = tile[tx][ty + i];
}

// ---------------- flash attention, LDS-staged K/V, 4 waves/block (R8, unchanged) ----------------
__launch_bounds__(256, 2)
__global__ void flash_attn(const short* __restrict__ qk, const short* __restrict__ vt,
                           float* __restrict__ O) {
  const int t = threadIdx.x;
  const int l = t & 63, w = t >> 6;
  const int lr = l & 15, lg = l >> 4;
  const int h = blockIdx.y;
  const int qb = blockIdx.x;
  __shared__ short Ks[2][64 * 64];
  __shared__ short Vs[2][64 * 64];
  __shared__ short Pl[4][16][72];
  const float C2 = 0.18033688011112042f;  // (1/sqrt(64)) * log2(e)

  const int qrow = qb * 64 + w * 16 + lr;
  short8 aq[2];
#pragma unroll
  for (int f = 0; f < 2; ++f)
    aq[f] = *(const short8*)(qk + (size_t)qrow * 2048 + h * 64 + f * 32 + lg * 8);

  f32x4 o[4] = {};
  float mrun = -1e30f, lrun = 0.0f;

  auto stage = [&](int b, int kt) {
#pragma unroll
    for (int i = 0; i < 2; ++i) {
      const int chunk = i * 256 + w * 64 + l;
      const int r = chunk >> 3, c = chunk & 7;
      const int cs = c ^ (r & 7);
      gload_lds16(qk + (size_t)(kt * 64 + r) * 2048 + h * 64 + cs * 8,
                  &Ks[b][(size_t)(i * 256 + w * 64) * 8]);
    }
#pragma unroll
    for (int i = 0; i < 2; ++i) {
      const int chunk = i * 256 + w * 64 + l;
      const int r = chunk >> 3, c = chunk & 7;
      const int cs = c ^ (r & 7);
      gload_lds16(vt + (size_t)(h * 64 + r) * 2048 + kt * 64 + cs * 8,
                  &Vs[b][(size_t)(i * 256 + w * 64) * 8]);
    }
  };

  stage(0, 0);
  __syncthreads();

#pragma unroll 1
  for (int kt = 0; kt < 32; ++kt) {
    const int cur = kt & 1;
    if (kt + 1 < 32) stage(cur ^ 1, kt + 1);

    f32x4 s[4] = {};
    __builtin_amdgcn_s_setprio(1);
#pragma unroll
    for (int f = 0; f < 2; ++f) {
      short8 kf[4];
#pragma unroll
      for (int n = 0; n < 4; ++n) {
        const int r = n * 16 + lr;
        kf[n] = *(const short8*)(&Ks[cur][r * 64 + (((f * 4 + lg) ^ (lr & 7)) * 8)]);
      }
#pragma unroll
      for (int n = 0; n < 4; ++n)
        s[n] = __builtin_amdgcn_mfma_f32_16x16x32_bf16(kf[n], aq[f], s[n], 0, 0, 0);
    }
    __builtin_amdgcn_s_setprio(0);
    float m0 = fmaxf(fmaxf(s[0][0], s[0][1]), fmaxf(s[0][2], s[0][3]));
    float m1 = fmaxf(fmaxf(s[1][0], s[1][1]), fmaxf(s[1][2], s[1][3]));
    float m2 = fmaxf(fmaxf(s[2][0], s[2][1]), fmaxf(s[2][2], s[2][3]));
    float m3 = fmaxf(fmaxf(s[3][0], s[3][1]), fmaxf(s[3][2], s[3][3]));
    float tm = fmaxf(fmaxf(m0, m1), fmaxf(m2, m3));
    tm = fmaxf(tm, __shfl_xor(tm, 16));
    tm = fmaxf(tm, __shfl_xor(tm, 32));
    float corrv = 1.0f;
    if (__any(tm > mrun)) {
      const float mnew = fmaxf(mrun, tm);
      corrv = fexp2((mrun - mnew) * C2);
      mrun = mnew;
      f32x4 cov;
#pragma unroll
      for (int r = 0; r < 4; ++r)
        cov[r] = __shfl(corrv, lg * 4 + r);
#pragma unroll
      for (int n = 0; n < 4; ++n)
        o[n] *= cov;
    }
    float p[4][4];
#pragma unroll
    for (int n = 0; n < 4; ++n)
#pragma unroll
      for (int r = 0; r < 4; ++r)
        p[n][r] = fexp2((s[n][r] - mrun) * C2);
    float q0 = (p[0][0] + p[0][1]) + (p[0][2] + p[0][3]);
    float q1 = (p[1][0] + p[1][1]) + (p[1][2] + p[1][3]);
    float q2 = (p[2][0] + p[2][1]) + (p[2][2] + p[2][3]);
    float q3 = (p[3][0] + p[3][1]) + (p[3][2] + p[3][3]);
    float ps = (q0 + q1) + (q2 + q3);
    ps += __shfl_xor(ps, 16);
    ps += __shfl_xor(ps, 32);
    lrun = lrun * corrv + ps;
#pragma unroll
    for (int n = 0; n < 4; ++n) {
      uint2 wv;
      wv.x = ((unsigned)(unsigned short)f2b(p[n][1]) << 16) | (unsigned short)f2b(p[n][0]);
      wv.y = ((unsigned)(unsigned short)f2b(p[n][3]) << 16) | (unsigned short)f2b(p[n][2]);
      *(uint2*)&Pl[w][lr][n * 16 + lg * 4] = wv;
    }
    __builtin_amdgcn_s_setprio(1);
#pragma unroll
    for (int f = 0; f < 2; ++f) {
      short8 ap = *(const short8*)&Pl[w][lr][f * 32 + lg * 8];
      short8 vf[4];
#pragma unroll
      for (int n = 0; n < 4; ++n) {
        const int r = n * 16 + lr;
        vf[n] = *(const short8*)(&Vs[cur][r * 64 + (((f * 4 + lg) ^ (lr & 7)) * 8)]);
      }
#pragma unroll
      for (int n = 0; n < 4; ++n)
        o[n] = __builtin_amdgcn_mfma_f32_16x16x32_bf16(ap, vf[n], o[n], 0, 0, 0);
    }
    __builtin_amdgcn_s_setprio(0);
    __syncthreads();
  }

  f32x4 inv;
#pragma unroll
  for (int r = 0; r < 4; ++r)
    inv[r] = 1.0f / __shfl(lrun, lg * 4 + r);
#pragma unroll
  for (int n = 0; n < 4; ++n)
#pragma unroll
    for (int r = 0; r < 4; ++r)
      O[(size_t)(qb * 64 + w * 16 + lg * 4 + r) * 1024 + h * 64 + n * 16 + lr] = o[n][r] * inv[r];
}

// ---------------- out = LN(A + B0 [+ B1] [+ bias]) * g + be ----------------
__launch_bounds__(256)
__global__ void add_ln(const float* __restrict__ A, const float* __restrict__ B0,
                       const float* __restrict__ B1, const float* __restrict__ bias,
                       const float* __restrict__ g, const float* __restrict__ be,
                       float* __restrict__ outf, short* __restrict__ outb) {
  const int row = blockIdx.x;
  const int t = threadIdx.x;
  const size_t base = (size_t)row * 1024 + t * 4;
  float4 a = *(const float4*)(A + base);
  float4 b = *(const float4*)(B0 + base);
  float4 s; s.x = a.x + b.x; s.y = a.y + b.y; s.z = a.z + b.z; s.w = a.w + b.w;
  if (B1) {
    float4 c = *(const float4*)(B1 + base);
    s.x += c.x; s.y += c.y; s.z += c.z; s.w += c.w;
  }
  if (bias) {
    float4 c = *(const float4*)(bias + t * 4);
    s.x += c.x; s.y += c.y; s.z += c.z; s.w += c.w;
  }
  float sum = s.x + s.y + s.z + s.w;
  float sq  = s.x * s.x + s.y * s.y + s.z * s.z + s.w * s.w;
#pragma unroll
  for (int d = 32; d > 0; d >>= 1) {
    sum += __shfl_down(sum, d);
    sq  += __shfl_down(sq, d);
  }
  __shared__ float red[8];
  const int w = t >> 6, l = t & 63;
  if (l == 0) { red[w] = sum; red[4 + w] = sq; }
  __syncthreads();
  sum = red[0] + red[1] + red[2] + red[3];
  sq  = red[4] + red[5] + red[6] + red[7];
  const float mu = sum * (1.0f / 1024.0f);
  const float rstd = rsqrtf(sq * (1.0f / 1024.0f) - mu * mu + 1e-5f);
  float4 gv = *(const float4*)(g + t * 4);
  float4 bv = *(const float4*)(be + t * 4);
  float4 o;
  o.x = (s.x - mu) * rstd * gv.x + bv.x;
  o.y = (s.y - mu) * rstd * gv.y + bv.y;
  o.z = (s.z - mu) * rstd * gv.z + bv.z;
  o.w = (s.w - mu) * rstd * gv.w + bv.w;
  *(float4*)(outf + base) = o;
  if (outb) {
    short4v ob; ob.x = f2b(o.x); ob.y = f2b(o.y); ob.z = f2b(o.z); ob.w = f2b(o.w);
    *(short4v*)(outb + base) = ob;
  }
}

extern "C" void kernel_launch(void* const* d_in, const int* in_sizes, int n_in,
                              void* d_out, int out_size, void* d_ws, size_t ws_size,
                              hipStream_t stream) {
  const float* X    = (const float*)d_in[0];
  const float* Wqkv = (const float*)d_in[1];
  const float* W1   = (const float*)d_in[2];
  const float* b1   = (const float*)d_in[3];
  const float* W2   = (const float*)d_in[4];
  const float* b2   = (const float*)d_in[5];
  const float* g1   = (const float*)d_in[6];
  const float* be1  = (const float*)d_in[7];
  const float* g2   = (const float*)d_in[8];
  const float* be2  = (const float*)d_in[9];

  // workspace, explicit offsets (60 MiB peak) — unchanged from R7/R8.
  char* ws = (char*)d_ws;
  const size_t MiB = 1u << 20;
  short*  W1b   = (short*)(ws + 0 * MiB);
  short*  W2b   = (short*)(ws + 8 * MiB);
  float*  h     = (float*)(ws + 16 * MiB);
  short*  hb    = (short*)(ws + 24 * MiB);
  short*  qkvb  = (short*)(ws + 28 * MiB);
  short*  y1b   = (short*)(ws + 28 * MiB);
  short*  vt    = (short*)(ws + 36 * MiB);
  float*  attn  = (float*)(ws + 44 * MiB);
  float*  P0    = (float*)(ws + 44 * MiB);
  float*  P1    = P0 + (size_t)NTOK * DMODEL;
  short*  Xb    = (short*)(ws + 52 * MiB);
  short*  Wqkvb = (short*)(ws + 56 * MiB);

  cast_all<<<6144, 256, 0, stream>>>(X, Xb, NTOK * DMODEL / 8,
                                     Wqkv, Wqkvb, 2 * DMODEL * DMODEL / 8,
                                     W1, W1b, DFF * DMODEL / 8,
                                     W2, W2b, DMODEL * DFF / 8);

  {  // qkv = X @ Wqkv^T -> bf16 [2048, 2048]; grid 512 (%8==0)
    dim3 grid(2 * DMODEL / 128, NTOK / 64, 1);
    gemm_bt<64, 128, 2, 2, true, false, false><<<grid, 256, 0, stream>>>(
        Xb, Wqkvb, nullptr, nullptr, qkvb, NTOK, 2 * DMODEL, DMODEL, DMODEL, DMODEL, 0);
  }
  {  // vt[d][n] = v[n][d]
    dim3 grid(DMODEL / 64, NTOK / 64);
    transpose_v<<<grid, 256, 0, stream>>>(qkvb, vt);
  }
  {  // attn_out f32 [2048, 1024]
    dim3 grid(NTOK / 64, NHEAD);
    flash_attn<<<grid, 256, 0, stream>>>(qkvb, vt, attn);
  }
  add_ln<<<NTOK, 256, 0, stream>>>(X, attn, nullptr, nullptr, g1, be1, h, hb);
  {  // y1 = relu(h @ W1^T + b1) -> bf16 [2048, 4096]; grid 1024
    dim3 grid(DFF / 128, NTOK / 64, 1);
    gemm_bt<64, 128, 2, 2, true, true, true><<<grid, 256, 0, stream>>>(
        hb, W1b, b1, nullptr, y1b, NTOK, DFF, DMODEL, DMODEL, DMODEL, 0);
  }
  {  // ffn2 partials: split-K=2; grid 256/z-slice (%8==0)
    dim3 grid(DMODEL / 128, NTOK / 64, 2);
    gemm_bt<64, 128, 2, 2, false, false, false><<<grid, 256, 0, stream>>>(
        y1b, W2b, nullptr, P0, nullptr, NTOK, DMODEL, 2048, DFF, DFF, 2048);
  }
  add_ln<<<NTOK, 256, 0, stream>>>(h, P0, P1, b2, g2, be2, (float*)d_out, nullptr);
}